// Round 2
// baseline (1528.454 us; speedup 1.0000x reference)
//
#include <hip/hip_runtime.h>
#include <hip/hip_bf16.h>

#define NN 100000
#define EE 3200000
#define NF 128
#define NH 256
#define NC 16
#define NB ((NN + 255) >> 8)   // 391 coarse buckets of 256 rows

typedef __bf16 bf16x8 __attribute__((ext_vector_type(8)));
typedef float f32x4 __attribute__((ext_vector_type(4)));

static __device__ __forceinline__ unsigned short f2bf(float f) {
    unsigned int u = __builtin_bit_cast(unsigned int, f);
    u += 0x7FFFu + ((u >> 16) & 1u);
    return (unsigned short)(u >> 16);
}
static __device__ __forceinline__ float b2f(unsigned short h) {
    unsigned int u = ((unsigned int)h) << 16;
    return __builtin_bit_cast(float, u);
}

// ---------- f32 -> bf16 convert (vector x4) ----------
__global__ void k_cvt_bf16(const float* __restrict__ in, unsigned short* __restrict__ out, int n) {
    int i = (blockIdx.x * blockDim.x + threadIdx.x) * 4;
    if (i + 3 < n) {
        float4 v = *(const float4*)(in + i);
        ushort4 o;
        o.x = f2bf(v.x); o.y = f2bf(v.y); o.z = f2bf(v.z); o.w = f2bf(v.w);
        *(ushort4*)(out + i) = o;
    } else {
        for (int t = 0; t < 4 && i + t < n; ++t) out[i + t] = f2bf(in[i + t]);
    }
}

// ---------- W[K,C] f32 -> Wt[C,K] bf16 ----------
__global__ void k_wT(const float* __restrict__ W, unsigned short* __restrict__ Wt, int K, int C) {
    int i = blockIdx.x * blockDim.x + threadIdx.x;
    if (i < K * C) {
        int k = i / C, c = i % C;
        Wt[c * K + k] = f2bf(W[i]);
    }
}

// ---------- CSR build ----------
__global__ void k_hist(const int* __restrict__ row, int* __restrict__ counts, int e) {
    int i = blockIdx.x * blockDim.x + threadIdx.x;
    if (i < e) atomicAdd(&counts[row[i]], 1);
}

__global__ void k_scan1(const int* __restrict__ counts, int* __restrict__ scanb,
                        int* __restrict__ parts, int n) {
    __shared__ int lds[256];
    int tid = threadIdx.x;
    int base = blockIdx.x * 1024 + tid * 4;
    int v[4]; int s = 0;
    for (int t = 0; t < 4; ++t) { v[t] = (base + t < n) ? counts[base + t] : 0; s += v[t]; }
    lds[tid] = s; __syncthreads();
    for (int off = 1; off < 256; off <<= 1) {
        int add = (tid >= off) ? lds[tid - off] : 0;
        __syncthreads();
        lds[tid] += add;
        __syncthreads();
    }
    int incl = lds[tid];
    int run = incl - s;
    for (int t = 0; t < 4; ++t) { run += v[t]; if (base + t < n) scanb[base + t] = run; }
    if (tid == 255) parts[blockIdx.x] = incl;
}

__global__ void k_scan2(int* __restrict__ parts, int np) {
    __shared__ int lds[128];
    int tid = threadIdx.x;
    int v = (tid < np) ? parts[tid] : 0;
    lds[tid] = v; __syncthreads();
    for (int off = 1; off < 128; off <<= 1) {
        int add = (tid >= off) ? lds[tid - off] : 0;
        __syncthreads();
        lds[tid] += add;
        __syncthreads();
    }
    parts[tid] = lds[tid] - v;  // exclusive
}

__global__ void k_scan3(const int* __restrict__ scanb, const int* __restrict__ parts,
                        int* __restrict__ rowp, int n) {
    int i = blockIdx.x * blockDim.x + threadIdx.x;
    if (i < n) {
        rowp[i + 1] = scanb[i] + parts[i >> 10];
        if (i == 0) rowp[0] = 0;
    }
}

// seed coarse-bucket cursors from rowp
__global__ void k_initbc(const int* __restrict__ rowp, int* __restrict__ bcur) {
    int b = blockIdx.x * blockDim.x + threadIdx.x;
    if (b < NB) bcur[b] = rowp[b << 8];
}

// ---------- Phase A: block-aggregated coarse binning (391 buckets of 256 rows) ----------
// record: high32 = val bits, low32 = col | (row&255)<<17   (col < 2^17)
__global__ __launch_bounds__(256) void k_binA(const int* __restrict__ row, const int* __restrict__ col,
                                              const float* __restrict__ val, int* __restrict__ bcur,
                                              unsigned long long* __restrict__ tmp, int e) {
    __shared__ int hist[NB];
    __shared__ int base[NB];
    int tid = threadIdx.x;
    int tile0 = blockIdx.x * 8192;
    for (int b = tid; b < NB; b += 256) hist[b] = 0;
    __syncthreads();
#pragma unroll 8
    for (int t = 0; t < 32; ++t) {
        int i = tile0 + t * 256 + tid;
        if (i < e) atomicAdd(&hist[row[i] >> 8], 1);
    }
    __syncthreads();
    for (int b = tid; b < NB; b += 256) {
        int c = hist[b];
        base[b] = c ? atomicAdd(&bcur[b], c) : 0;
        hist[b] = 0;
    }
    __syncthreads();
#pragma unroll 8
    for (int t = 0; t < 32; ++t) {
        int i = tile0 + t * 256 + tid;
        if (i < e) {
            int r = row[i];
            int b = r >> 8;
            int rk = atomicAdd(&hist[b], 1);
            unsigned long long rec = ((unsigned long long)__builtin_bit_cast(unsigned int, val[i]) << 32)
                                   | (unsigned int)(col[i] | ((r & 255) << 17));
            tmp[base[b] + rk] = rec;
        }
    }
}

// ---------- Phase B: per-bucket fine sort to CSR via LDS cursors ----------
__global__ __launch_bounds__(256) void k_binB(const int* __restrict__ rowp,
                                              const unsigned long long* __restrict__ tmp,
                                              unsigned long long* __restrict__ pairs, int n) {
    __shared__ int cur[256];
    int tid = threadIdx.x;
    int r0 = blockIdx.x << 8;
    int s = rowp[r0];
    int eEnd = rowp[min(r0 + 256, n)];
    int rr = r0 + tid;
    cur[tid] = (rr < n) ? rowp[rr] : 0;  // rows >= n never occur
    __syncthreads();
    for (int i = s + tid; i < eEnd; i += 256) {
        unsigned long long rec = tmp[i];
        unsigned int w = (unsigned int)rec;
        int r = (w >> 17) & 255;
        int pos = atomicAdd(&cur[r], 1);
        pairs[pos] = (rec & 0xFFFFFFFF00000000ULL) | (unsigned long long)(w & 0x1FFFFu);
    }
}

// ---------- MFMA bf16 GEMM: C[M,256] = A[M,K] @ Bt[256,K]^T, optional bias+relu ----------
template <bool BR>
__global__ __launch_bounds__(256) void k_gemm(const unsigned short* __restrict__ A,
                                              const unsigned short* __restrict__ Bt,
                                              const float* __restrict__ bias,
                                              unsigned short* __restrict__ C,
                                              int M, int K) {
    int wave = threadIdx.x >> 6, lane = threadIdx.x & 63;
    int row0 = blockIdx.x * 64;
    int colBase = wave * 64;
    int hr = lane & 15, kg = lane >> 4;
    f32x4 acc[4][4];
#pragma unroll
    for (int r = 0; r < 4; ++r)
#pragma unroll
        for (int c = 0; c < 4; ++c) acc[r][c] = (f32x4){0.f, 0.f, 0.f, 0.f};

    for (int k0 = 0; k0 < K; k0 += 32) {
        int kk = k0 + kg * 8;
        bf16x8 af[4], bf_[4];
#pragma unroll
        for (int r = 0; r < 4; ++r) {
            int ar = row0 + r * 16 + hr;
            if (ar >= M) ar = M - 1;
            af[r] = *(const bf16x8*)(A + (size_t)ar * K + kk);
        }
#pragma unroll
        for (int c = 0; c < 4; ++c) {
            int bc = colBase + c * 16 + hr;
            bf_[c] = *(const bf16x8*)(Bt + (size_t)bc * K + kk);
        }
#pragma unroll
        for (int r = 0; r < 4; ++r)
#pragma unroll
            for (int c = 0; c < 4; ++c)
                acc[r][c] = __builtin_amdgcn_mfma_f32_16x16x32_bf16(af[r], bf_[c], acc[r][c], 0, 0, 0);
    }
    // C/D layout: col = lane&15, row = (lane>>4)*4 + reg
#pragma unroll
    for (int r = 0; r < 4; ++r)
#pragma unroll
        for (int c = 0; c < 4; ++c) {
            int col = colBase + c * 16 + hr;
            float bv = BR ? bias[col] : 0.f;
#pragma unroll
            for (int i = 0; i < 4; ++i) {
                int rr = row0 + r * 16 + kg * 4 + i;
                float v = acc[r][c][i];
                if (BR) v = fmaxf(v + bv, 0.f);
                if (rr < M) C[(size_t)rr * 256 + col] = f2bf(v);
            }
        }
}

// ---------- SpMM D=256: out[row] = relu(sum val*S[col] + bias) ----------
// cooperative 64-edge preload + readlane scalarization: gathers issue from SGPR base,
// no per-edge dependent pairs load.
__global__ __launch_bounds__(256) void k_spmm256(const int* __restrict__ rowp,
                                                 const unsigned long long* __restrict__ pairs,
                                                 const unsigned short* __restrict__ S,
                                                 const float* __restrict__ bias,
                                                 unsigned short* __restrict__ Hout, int n) {
    int lane = threadIdx.x & 63;
    int row = blockIdx.x * 4 + (threadIdx.x >> 6);
    if (row >= n) return;
    int s = rowp[row], e = rowp[row + 1];
    int f = lane * 4;
    const unsigned short* Sf = S + f;
    float a0 = 0.f, a1 = 0.f, a2 = 0.f, a3 = 0.f;
    for (int base = s; base < e; base += 64) {
        int cnt = min(64, e - base);
        // one coalesced 512B load covers the next 64 edges for the whole wave
        unsigned long long myp = pairs[base + min(lane, cnt - 1)];
        unsigned int mycol = (unsigned int)myp;
        unsigned int myval = (unsigned int)(myp >> 32);
#pragma unroll 4
        for (int j = 0; j < cnt; ++j) {
            unsigned int c = (unsigned int)__builtin_amdgcn_readlane((int)mycol, j);
            float v = __builtin_bit_cast(float, (unsigned int)__builtin_amdgcn_readlane((int)myval, j));
            ushort4 t = *(const ushort4*)(Sf + (size_t)c * 256);
            a0 += v * b2f(t.x); a1 += v * b2f(t.y); a2 += v * b2f(t.z); a3 += v * b2f(t.w);
        }
    }
    a0 = fmaxf(a0 + bias[f], 0.f);
    a1 = fmaxf(a1 + bias[f + 1], 0.f);
    a2 = fmaxf(a2 + bias[f + 2], 0.f);
    a3 = fmaxf(a3 + bias[f + 3], 0.f);
    ushort4 o; o.x = f2bf(a0); o.y = f2bf(a1); o.z = f2bf(a2); o.w = f2bf(a3);
    *(ushort4*)(Hout + (size_t)row * 256 + f) = o;
}

// ---------- SpMM D=128, no bias/relu: out[row] = sum val*X[col] (layer-1 aggregation) ----------
__global__ __launch_bounds__(256) void k_spmm128(const int* __restrict__ rowp,
                                                 const unsigned long long* __restrict__ pairs,
                                                 const unsigned short* __restrict__ X,
                                                 unsigned short* __restrict__ Out, int n) {
    int lane = threadIdx.x & 63;
    int row = blockIdx.x * 4 + (threadIdx.x >> 6);
    if (row >= n) return;
    int s = rowp[row], e = rowp[row + 1];
    int f = lane * 2;
    const unsigned short* Xf = X + f;
    float a0 = 0.f, a1 = 0.f;
    for (int base = s; base < e; base += 64) {
        int cnt = min(64, e - base);
        unsigned long long myp = pairs[base + min(lane, cnt - 1)];
        unsigned int mycol = (unsigned int)myp;
        unsigned int myval = (unsigned int)(myp >> 32);
#pragma unroll 4
        for (int j = 0; j < cnt; ++j) {
            unsigned int c = (unsigned int)__builtin_amdgcn_readlane((int)mycol, j);
            float v = __builtin_bit_cast(float, (unsigned int)__builtin_amdgcn_readlane((int)myval, j));
            ushort2 t = *(const ushort2*)(Xf + (size_t)c * 128);
            a0 += v * b2f(t.x); a1 += v * b2f(t.y);
        }
    }
    ushort2 o; o.x = f2bf(a0); o.y = f2bf(a1);
    *(ushort2*)(Out + (size_t)row * 128 + f) = o;
}

// ---------- FC + log_softmax: 16 lanes per node ----------
__global__ __launch_bounds__(256) void k_fc_lsm(const unsigned short* __restrict__ H,
                                                const float* __restrict__ Wf,
                                                const float* __restrict__ bf,
                                                float* __restrict__ out, int n) {
    int lane = threadIdx.x & 63;
    int wave = threadIdx.x >> 6;
    int sub = lane >> 4, j = lane & 15;
    int node = (blockIdx.x * 4 + wave) * 4 + sub;
    bool valid = node < n;
    int nd = valid ? node : (n - 1);
    float acc = 0.f;
    for (int f0 = 0; f0 < NH; f0 += 8) {
        union { uint4 u; unsigned short s[8]; } h;
        h.u = *(const uint4*)(H + (size_t)nd * NH + f0);
#pragma unroll
        for (int t = 0; t < 8; ++t) acc += b2f(h.s[t]) * Wf[(f0 + t) * NC + j];
    }
    acc += bf[j];
    float mx = acc;
    for (int m = 1; m < 16; m <<= 1) mx = fmaxf(mx, __shfl_xor(mx, m, 16));
    float sm = __expf(acc - mx);
    for (int m = 1; m < 16; m <<= 1) sm += __shfl_xor(sm, m, 16);
    float res = acc - mx - __logf(sm);
    if (valid) out[(size_t)node * NC + j] = res;
}

extern "C" void kernel_launch(void* const* d_in, const int* in_sizes, int n_in,
                              void* d_out, int out_size, void* d_ws, size_t ws_size,
                              hipStream_t stream) {
    const float* x      = (const float*)d_in[0];
    const float* adjval = (const float*)d_in[1];
    const float* w1 = (const float*)d_in[2];  const float* b1 = (const float*)d_in[3];
    const float* w2 = (const float*)d_in[4];  const float* b2 = (const float*)d_in[5];
    const float* w3 = (const float*)d_in[6];  const float* b3 = (const float*)d_in[7];
    const float* w4 = (const float*)d_in[8];  const float* b4 = (const float*)d_in[9];
    const float* fcw = (const float*)d_in[10]; const float* fcb = (const float*)d_in[11];
    const int* arow = (const int*)d_in[12];
    const int* acol = (const int*)d_in[13];
    float* out = (float*)d_out;

    char* ws = (char*)d_ws;
    size_t off = 0;
    auto alloc = [&](size_t bytes) { size_t o = off; off += (bytes + 255) & ~(size_t)255; return o; };

    unsigned short* xb  = (unsigned short*)(ws + alloc((size_t)NN * NF * 2));
    unsigned short* Sb  = (unsigned short*)(ws + alloc((size_t)NN * NH * 2));  // also holds Ax [N,128] for layer 1
    unsigned short* H1  = (unsigned short*)(ws + alloc((size_t)NN * NH * 2));
    unsigned short* H2  = (unsigned short*)(ws + alloc((size_t)NN * NH * 2));
    unsigned short* Wt1 = (unsigned short*)(ws + alloc((size_t)NH * NF * 2));
    unsigned short* Wt2 = (unsigned short*)(ws + alloc((size_t)NH * NH * 2));
    unsigned short* Wt3 = (unsigned short*)(ws + alloc((size_t)NH * NH * 2));
    unsigned short* Wt4 = (unsigned short*)(ws + alloc((size_t)NH * NH * 2));
    int*   counts = (int*)(ws + alloc((size_t)NN * 4));
    int*   scanb  = (int*)(ws + alloc((size_t)NN * 4));
    int*   parts  = (int*)(ws + alloc(128 * 4));
    int*   rowp   = (int*)(ws + alloc(((size_t)NN + 1) * 4));
    int*   bcur   = (int*)(ws + alloc((size_t)NB * 4));
    unsigned long long* pairs = (unsigned long long*)(ws + alloc((size_t)EE * 8));
    // tmp for binning reuses H2 (dead until layer 2; 51.2MB >= 25.6MB)
    unsigned long long* tmp = (unsigned long long*)H2;

    // --- input conversions ---
    k_cvt_bf16<<<(NN * NF / 4 + 255) / 256, 256, 0, stream>>>(x, xb, NN * NF);
    k_wT<<<(NF * NH + 255) / 256, 256, 0, stream>>>(w1, Wt1, NF, NH);
    k_wT<<<(NH * NH + 255) / 256, 256, 0, stream>>>(w2, Wt2, NH, NH);
    k_wT<<<(NH * NH + 255) / 256, 256, 0, stream>>>(w3, Wt3, NH, NH);
    k_wT<<<(NH * NH + 255) / 256, 256, 0, stream>>>(w4, Wt4, NH, NH);

    // --- CSR build ---
    hipMemsetAsync(counts, 0, (size_t)NN * 4, stream);
    k_hist<<<(EE + 255) / 256, 256, 0, stream>>>(arow, counts, EE);
    int nscan = (NN + 1023) / 1024;  // 98
    k_scan1<<<nscan, 256, 0, stream>>>(counts, scanb, parts, NN);
    k_scan2<<<1, 128, 0, stream>>>(parts, nscan);
    k_scan3<<<(NN + 255) / 256, 256, 0, stream>>>(scanb, parts, rowp, NN);
    k_initbc<<<(NB + 255) / 256, 256, 0, stream>>>(rowp, bcur);
    // two-phase write-coalesced counting sort (replaces random-scatter k_scatter)
    k_binA<<<(EE + 8191) / 8192, 256, 0, stream>>>(arow, acol, adjval, bcur, tmp, EE);
    k_binB<<<NB, 256, 0, stream>>>(rowp, tmp, pairs, NN);

    int gGemm = (NN + 63) / 64;     // 1563
    int gSpmm = (NN + 3) / 4;       // 25000
    // --- layer 1 (reordered: (A@x)@W1, gathers 128 feats instead of 256) ---
    k_spmm128<<<gSpmm, 256, 0, stream>>>(rowp, pairs, xb, Sb, NN);
    k_gemm<true><<<gGemm, 256, 0, stream>>>(Sb, Wt1, b1, H1, NN, NF);
    // --- layer 2 ---
    k_gemm<false><<<gGemm, 256, 0, stream>>>(H1, Wt2, nullptr, Sb, NN, NH);
    k_spmm256<<<gSpmm, 256, 0, stream>>>(rowp, pairs, Sb, b2, H2, NN);
    // --- layer 3 ---
    k_gemm<false><<<gGemm, 256, 0, stream>>>(H2, Wt3, nullptr, Sb, NN, NH);
    k_spmm256<<<gSpmm, 256, 0, stream>>>(rowp, pairs, Sb, b3, H1, NN);
    // --- layer 4 ---
    k_gemm<false><<<gGemm, 256, 0, stream>>>(H1, Wt4, nullptr, Sb, NN, NH);
    k_spmm256<<<gSpmm, 256, 0, stream>>>(rowp, pairs, Sb, b4, H2, NN);
    // --- FC + log_softmax ---
    k_fc_lsm<<<(NN + 15) / 16, 256, 0, stream>>>(H2, fcw, fcb, out, NN);
}

// Round 3
// 1422.250 us; speedup vs baseline: 1.0747x; 1.0747x over previous
//
#include <hip/hip_runtime.h>
#include <hip/hip_bf16.h>

#define NN 100000
#define EE 3200000
#define NF 128
#define NH 256
#define NC 16
#define NB ((NN + 255) >> 8)          // 391 coarse buckets of 256 rows
#define TILEA 8192
#define NBLKA ((EE + TILEA - 1) / TILEA)  // 391 binning blocks

typedef __bf16 bf16x8 __attribute__((ext_vector_type(8)));
typedef float f32x4 __attribute__((ext_vector_type(4)));

static __device__ __forceinline__ unsigned short f2bf(float f) {
    unsigned int u = __builtin_bit_cast(unsigned int, f);
    u += 0x7FFFu + ((u >> 16) & 1u);
    return (unsigned short)(u >> 16);
}
static __device__ __forceinline__ float b2f(unsigned short h) {
    unsigned int u = ((unsigned int)h) << 16;
    return __builtin_bit_cast(float, u);
}

// ---------- f32 -> bf16 convert (vector x4) ----------
__global__ void k_cvt_bf16(const float* __restrict__ in, unsigned short* __restrict__ out, int n) {
    int i = (blockIdx.x * blockDim.x + threadIdx.x) * 4;
    if (i + 3 < n) {
        float4 v = *(const float4*)(in + i);
        ushort4 o;
        o.x = f2bf(v.x); o.y = f2bf(v.y); o.z = f2bf(v.z); o.w = f2bf(v.w);
        *(ushort4*)(out + i) = o;
    } else {
        for (int t = 0; t < 4 && i + t < n; ++t) out[i + t] = f2bf(in[i + t]);
    }
}

// ---------- W[K,C] f32 -> Wt[C,K] bf16 ----------
__global__ void k_wT(const float* __restrict__ W, unsigned short* __restrict__ Wt, int K, int C) {
    int i = blockIdx.x * blockDim.x + threadIdx.x;
    if (i < K * C) {
        int k = i / C, c = i % C;
        Wt[c * K + k] = f2bf(W[i]);
    }
}

// ---------- CSR build ----------
__global__ void k_hist(const int* __restrict__ row, int* __restrict__ counts, int e) {
    int i = blockIdx.x * blockDim.x + threadIdx.x;
    if (i < e) atomicAdd(&counts[row[i]], 1);
}

__global__ void k_scan1(const int* __restrict__ counts, int* __restrict__ scanb,
                        int* __restrict__ parts, int n) {
    __shared__ int lds[256];
    int tid = threadIdx.x;
    int base = blockIdx.x * 1024 + tid * 4;
    int v[4]; int s = 0;
    for (int t = 0; t < 4; ++t) { v[t] = (base + t < n) ? counts[base + t] : 0; s += v[t]; }
    lds[tid] = s; __syncthreads();
    for (int off = 1; off < 256; off <<= 1) {
        int add = (tid >= off) ? lds[tid - off] : 0;
        __syncthreads();
        lds[tid] += add;
        __syncthreads();
    }
    int incl = lds[tid];
    int run = incl - s;
    for (int t = 0; t < 4; ++t) { run += v[t]; if (base + t < n) scanb[base + t] = run; }
    if (tid == 255) parts[blockIdx.x] = incl;
}

__global__ void k_scan2(int* __restrict__ parts, int np) {
    __shared__ int lds[128];
    int tid = threadIdx.x;
    int v = (tid < np) ? parts[tid] : 0;
    lds[tid] = v; __syncthreads();
    for (int off = 1; off < 128; off <<= 1) {
        int add = (tid >= off) ? lds[tid - off] : 0;
        __syncthreads();
        lds[tid] += add;
        __syncthreads();
    }
    parts[tid] = lds[tid] - v;  // exclusive
}

__global__ void k_scan3(const int* __restrict__ scanb, const int* __restrict__ parts,
                        int* __restrict__ rowp, int n) {
    int i = blockIdx.x * blockDim.x + threadIdx.x;
    if (i < n) {
        rowp[i + 1] = scanb[i] + parts[i >> 10];
        if (i == 0) rowp[0] = 0;
    }
}

// ---------- binning pass 1: per-(block,bucket) counts (LDS atomics only) ----------
// cmat layout column-major: cmat[b * NBLKA + blk]
__global__ __launch_bounds__(256) void k_cnt(const int* __restrict__ row, int* __restrict__ cmat, int e) {
    __shared__ int hist[NB];
    int tid = threadIdx.x;
    int tile0 = blockIdx.x * TILEA;
    for (int b = tid; b < NB; b += 256) hist[b] = 0;
    __syncthreads();
#pragma unroll 8
    for (int t = 0; t < TILEA / 256; ++t) {
        int i = tile0 + t * 256 + tid;
        if (i < e) atomicAdd(&hist[row[i] >> 8], 1);
    }
    __syncthreads();
    for (int b = tid; b < NB; b += 256) cmat[b * NBLKA + blockIdx.x] = hist[b];
}

// ---------- binning pass 2: exclusive scan of each bucket's column + rowp base ----------
__global__ __launch_bounds__(512) void k_cscan(int* __restrict__ cmat, const int* __restrict__ rowp) {
    __shared__ int lds[512];
    int b = blockIdx.x, tid = threadIdx.x;
    int v = (tid < NBLKA) ? cmat[b * NBLKA + tid] : 0;
    lds[tid] = v; __syncthreads();
    for (int off = 1; off < 512; off <<= 1) {
        int add = (tid >= off) ? lds[tid - off] : 0;
        __syncthreads();
        lds[tid] += add;
        __syncthreads();
    }
    if (tid < NBLKA) cmat[b * NBLKA + tid] = rowp[b << 8] + lds[tid] - v;  // exclusive + base
}

// ---------- binning pass 3: scatter to bucket-grouped tmp at scanned bases ----------
// record: high32 = val bits, low32 = col | (row&255)<<17   (col < 2^17)
__global__ __launch_bounds__(256) void k_scat2(const int* __restrict__ row, const int* __restrict__ col,
                                               const float* __restrict__ val, const int* __restrict__ cmat,
                                               unsigned long long* __restrict__ tmp, int e) {
    __shared__ int hist[NB];
    __shared__ int base[NB];
    int tid = threadIdx.x;
    int tile0 = blockIdx.x * TILEA;
    for (int b = tid; b < NB; b += 256) {
        base[b] = cmat[b * NBLKA + blockIdx.x];
        hist[b] = 0;
    }
    __syncthreads();
#pragma unroll 8
    for (int t = 0; t < TILEA / 256; ++t) {
        int i = tile0 + t * 256 + tid;
        if (i < e) {
            int r = row[i];
            int b = r >> 8;
            int rk = atomicAdd(&hist[b], 1);
            unsigned long long rec = ((unsigned long long)__builtin_bit_cast(unsigned int, val[i]) << 32)
                                   | (unsigned int)(col[i] | ((r & 255) << 17));
            tmp[base[b] + rk] = rec;
        }
    }
}

// ---------- binning pass 4: per-bucket fine sort to CSR via LDS cursors ----------
__global__ __launch_bounds__(256) void k_binB(const int* __restrict__ rowp,
                                              const unsigned long long* __restrict__ tmp,
                                              unsigned long long* __restrict__ pairs, int n) {
    __shared__ int cur[256];
    int tid = threadIdx.x;
    int r0 = blockIdx.x << 8;
    int s = rowp[r0];
    int eEnd = rowp[min(r0 + 256, n)];
    int rr = r0 + tid;
    cur[tid] = (rr < n) ? rowp[rr] : 0;  // rows >= n never occur
    __syncthreads();
    for (int i = s + tid; i < eEnd; i += 256) {
        unsigned long long rec = tmp[i];
        unsigned int w = (unsigned int)rec;
        int r = (w >> 17) & 255;
        int pos = atomicAdd(&cur[r], 1);
        pairs[pos] = (rec & 0xFFFFFFFF00000000ULL) | (unsigned long long)(w & 0x1FFFFu);
    }
}

// ---------- MFMA bf16 GEMM: C[M,256] = A[M,K] @ Bt[256,K]^T, optional bias+relu ----------
template <bool BR>
__global__ __launch_bounds__(256) void k_gemm(const unsigned short* __restrict__ A,
                                              const unsigned short* __restrict__ Bt,
                                              const float* __restrict__ bias,
                                              unsigned short* __restrict__ C,
                                              int M, int K) {
    int wave = threadIdx.x >> 6, lane = threadIdx.x & 63;
    int row0 = blockIdx.x * 64;
    int colBase = wave * 64;
    int hr = lane & 15, kg = lane >> 4;
    f32x4 acc[4][4];
#pragma unroll
    for (int r = 0; r < 4; ++r)
#pragma unroll
        for (int c = 0; c < 4; ++c) acc[r][c] = (f32x4){0.f, 0.f, 0.f, 0.f};

    for (int k0 = 0; k0 < K; k0 += 32) {
        int kk = k0 + kg * 8;
        bf16x8 af[4], bf_[4];
#pragma unroll
        for (int r = 0; r < 4; ++r) {
            int ar = row0 + r * 16 + hr;
            if (ar >= M) ar = M - 1;
            af[r] = *(const bf16x8*)(A + (size_t)ar * K + kk);
        }
#pragma unroll
        for (int c = 0; c < 4; ++c) {
            int bc = colBase + c * 16 + hr;
            bf_[c] = *(const bf16x8*)(Bt + (size_t)bc * K + kk);
        }
#pragma unroll
        for (int r = 0; r < 4; ++r)
#pragma unroll
            for (int c = 0; c < 4; ++c)
                acc[r][c] = __builtin_amdgcn_mfma_f32_16x16x32_bf16(af[r], bf_[c], acc[r][c], 0, 0, 0);
    }
    // C/D layout: col = lane&15, row = (lane>>4)*4 + reg
#pragma unroll
    for (int r = 0; r < 4; ++r)
#pragma unroll
        for (int c = 0; c < 4; ++c) {
            int col = colBase + c * 16 + hr;
            float bv = BR ? bias[col] : 0.f;
#pragma unroll
            for (int i = 0; i < 4; ++i) {
                int rr = row0 + r * 16 + kg * 4 + i;
                float v = acc[r][c][i];
                if (BR) v = fmaxf(v + bv, 0.f);
                if (rr < M) C[(size_t)rr * 256 + col] = f2bf(v);
            }
        }
}

// ---------- SpMM D=256: out[row] = relu(sum val*S[col] + bias) ----------
__global__ __launch_bounds__(256) void k_spmm256(const int* __restrict__ rowp,
                                                 const unsigned long long* __restrict__ pairs,
                                                 const unsigned short* __restrict__ S,
                                                 const float* __restrict__ bias,
                                                 unsigned short* __restrict__ Hout, int n) {
    int lane = threadIdx.x & 63;
    int row = blockIdx.x * 4 + (threadIdx.x >> 6);
    if (row >= n) return;
    int s = rowp[row], e = rowp[row + 1];
    int f = lane * 4;
    float a0 = 0.f, a1 = 0.f, a2 = 0.f, a3 = 0.f;
#pragma unroll 8
    for (int i = s; i < e; ++i) {
        unsigned long long p = pairs[i];
        int c = (int)(unsigned int)p;
        float v = __builtin_bit_cast(float, (unsigned int)(p >> 32));
        ushort4 t = *(const ushort4*)(S + (size_t)c * 256 + f);
        a0 += v * b2f(t.x); a1 += v * b2f(t.y); a2 += v * b2f(t.z); a3 += v * b2f(t.w);
    }
    float4 bv = *(const float4*)(bias + f);
    a0 = fmaxf(a0 + bv.x, 0.f);
    a1 = fmaxf(a1 + bv.y, 0.f);
    a2 = fmaxf(a2 + bv.z, 0.f);
    a3 = fmaxf(a3 + bv.w, 0.f);
    ushort4 o; o.x = f2bf(a0); o.y = f2bf(a1); o.z = f2bf(a2); o.w = f2bf(a3);
    *(ushort4*)(Hout + (size_t)row * 256 + f) = o;
}

// ---------- SpMM D=128, no bias/relu: out[row] = sum val*X[col] (layer-1 aggregation) ----------
__global__ __launch_bounds__(256) void k_spmm128(const int* __restrict__ rowp,
                                                 const unsigned long long* __restrict__ pairs,
                                                 const unsigned short* __restrict__ X,
                                                 unsigned short* __restrict__ Out, int n) {
    int lane = threadIdx.x & 63;
    int row = blockIdx.x * 4 + (threadIdx.x >> 6);
    if (row >= n) return;
    int s = rowp[row], e = rowp[row + 1];
    int f = lane * 2;
    float a0 = 0.f, a1 = 0.f;
#pragma unroll 8
    for (int i = s; i < e; ++i) {
        unsigned long long p = pairs[i];
        int c = (int)(unsigned int)p;
        float v = __builtin_bit_cast(float, (unsigned int)(p >> 32));
        ushort2 t = *(const ushort2*)(X + (size_t)c * 128 + f);
        a0 += v * b2f(t.x); a1 += v * b2f(t.y);
    }
    ushort2 o; o.x = f2bf(a0); o.y = f2bf(a1);
    *(ushort2*)(Out + (size_t)row * 128 + f) = o;
}

// ---------- FC + log_softmax: 16 lanes per node ----------
__global__ __launch_bounds__(256) void k_fc_lsm(const unsigned short* __restrict__ H,
                                                const float* __restrict__ Wf,
                                                const float* __restrict__ bf,
                                                float* __restrict__ out, int n) {
    int lane = threadIdx.x & 63;
    int wave = threadIdx.x >> 6;
    int sub = lane >> 4, j = lane & 15;
    int node = (blockIdx.x * 4 + wave) * 4 + sub;
    bool valid = node < n;
    int nd = valid ? node : (n - 1);
    float acc = 0.f;
    for (int f0 = 0; f0 < NH; f0 += 8) {
        union { uint4 u; unsigned short s[8]; } h;
        h.u = *(const uint4*)(H + (size_t)nd * NH + f0);
#pragma unroll
        for (int t = 0; t < 8; ++t) acc += b2f(h.s[t]) * Wf[(f0 + t) * NC + j];
    }
    acc += bf[j];
    float mx = acc;
    for (int m = 1; m < 16; m <<= 1) mx = fmaxf(mx, __shfl_xor(mx, m, 16));
    float sm = __expf(acc - mx);
    for (int m = 1; m < 16; m <<= 1) sm += __shfl_xor(sm, m, 16);
    float res = acc - mx - __logf(sm);
    if (valid) out[(size_t)node * NC + j] = res;
}

extern "C" void kernel_launch(void* const* d_in, const int* in_sizes, int n_in,
                              void* d_out, int out_size, void* d_ws, size_t ws_size,
                              hipStream_t stream) {
    const float* x      = (const float*)d_in[0];
    const float* adjval = (const float*)d_in[1];
    const float* w1 = (const float*)d_in[2];  const float* b1 = (const float*)d_in[3];
    const float* w2 = (const float*)d_in[4];  const float* b2 = (const float*)d_in[5];
    const float* w3 = (const float*)d_in[6];  const float* b3 = (const float*)d_in[7];
    const float* w4 = (const float*)d_in[8];  const float* b4 = (const float*)d_in[9];
    const float* fcw = (const float*)d_in[10]; const float* fcb = (const float*)d_in[11];
    const int* arow = (const int*)d_in[12];
    const int* acol = (const int*)d_in[13];
    float* out = (float*)d_out;

    char* ws = (char*)d_ws;
    size_t off = 0;
    auto alloc = [&](size_t bytes) { size_t o = off; off += (bytes + 255) & ~(size_t)255; return o; };

    unsigned short* xb  = (unsigned short*)(ws + alloc((size_t)NN * NF * 2));
    unsigned short* Sb  = (unsigned short*)(ws + alloc((size_t)NN * NH * 2));  // also holds Ax [N,128] for layer 1
    unsigned short* H1  = (unsigned short*)(ws + alloc((size_t)NN * NH * 2));
    unsigned short* H2  = (unsigned short*)(ws + alloc((size_t)NN * NH * 2));
    unsigned short* Wt1 = (unsigned short*)(ws + alloc((size_t)NH * NF * 2));
    unsigned short* Wt2 = (unsigned short*)(ws + alloc((size_t)NH * NH * 2));
    unsigned short* Wt3 = (unsigned short*)(ws + alloc((size_t)NH * NH * 2));
    unsigned short* Wt4 = (unsigned short*)(ws + alloc((size_t)NH * NH * 2));
    int*   counts = (int*)(ws + alloc((size_t)NN * 4));
    int*   scanb  = (int*)(ws + alloc((size_t)NN * 4));
    int*   parts  = (int*)(ws + alloc(128 * 4));
    int*   rowp   = (int*)(ws + alloc(((size_t)NN + 1) * 4));
    int*   cmat   = (int*)(ws + alloc((size_t)NB * NBLKA * 4));
    unsigned long long* pairs = (unsigned long long*)(ws + alloc((size_t)EE * 8));
    // tmp for binning reuses H2 (dead until layer 2; 51.2MB >= 25.6MB)
    unsigned long long* tmp = (unsigned long long*)H2;

    // --- input conversions ---
    k_cvt_bf16<<<(NN * NF / 4 + 255) / 256, 256, 0, stream>>>(x, xb, NN * NF);
    k_wT<<<(NF * NH + 255) / 256, 256, 0, stream>>>(w1, Wt1, NF, NH);
    k_wT<<<(NH * NH + 255) / 256, 256, 0, stream>>>(w2, Wt2, NH, NH);
    k_wT<<<(NH * NH + 255) / 256, 256, 0, stream>>>(w3, Wt3, NH, NH);
    k_wT<<<(NH * NH + 255) / 256, 256, 0, stream>>>(w4, Wt4, NH, NH);

    // --- CSR build ---
    hipMemsetAsync(counts, 0, (size_t)NN * 4, stream);
    k_hist<<<(EE + 255) / 256, 256, 0, stream>>>(arow, counts, EE);
    int nscan = (NN + 1023) / 1024;  // 98
    k_scan1<<<nscan, 256, 0, stream>>>(counts, scanb, parts, NN);
    k_scan2<<<1, 128, 0, stream>>>(parts, nscan);
    k_scan3<<<(NN + 255) / 256, 256, 0, stream>>>(scanb, parts, rowp, NN);
    // atomic-free counting-sort binning: count -> column-scan -> scatter -> fine sort
    k_cnt<<<NBLKA, 256, 0, stream>>>(arow, cmat, EE);
    k_cscan<<<NB, 512, 0, stream>>>(cmat, rowp);
    k_scat2<<<NBLKA, 256, 0, stream>>>(arow, acol, adjval, cmat, tmp, EE);
    k_binB<<<NB, 256, 0, stream>>>(rowp, tmp, pairs, NN);

    int gGemm = (NN + 63) / 64;     // 1563
    int gSpmm = (NN + 3) / 4;       // 25000
    // --- layer 1 (reordered: (A@x)@W1, gathers 128 feats instead of 256) ---
    k_spmm128<<<gSpmm, 256, 0, stream>>>(rowp, pairs, xb, Sb, NN);
    k_gemm<true><<<gGemm, 256, 0, stream>>>(Sb, Wt1, b1, H1, NN, NF);
    // --- layer 2 ---
    k_gemm<false><<<gGemm, 256, 0, stream>>>(H1, Wt2, nullptr, Sb, NN, NH);
    k_spmm256<<<gSpmm, 256, 0, stream>>>(rowp, pairs, Sb, b2, H2, NN);
    // --- layer 3 ---
    k_gemm<false><<<gGemm, 256, 0, stream>>>(H2, Wt3, nullptr, Sb, NN, NH);
    k_spmm256<<<gSpmm, 256, 0, stream>>>(rowp, pairs, Sb, b3, H1, NN);
    // --- layer 4 ---
    k_gemm<false><<<gGemm, 256, 0, stream>>>(H1, Wt4, nullptr, Sb, NN, NH);
    k_spmm256<<<gSpmm, 256, 0, stream>>>(rowp, pairs, Sb, b4, H2, NN);
    // --- FC + log_softmax ---
    k_fc_lsm<<<(NN + 15) / 16, 256, 0, stream>>>(H2, fcw, fcb, out, NN);
}

// Round 4
// 1417.146 us; speedup vs baseline: 1.0785x; 1.0036x over previous
//
#include <hip/hip_runtime.h>
#include <hip/hip_bf16.h>

#define NN 100000
#define EE 3200000
#define NF 128
#define NH 256
#define NC 16
#define NB ((NN + 255) >> 8)          // 391 coarse buckets of 256 rows
#define TILEA 8192
#define NBLKA ((EE + TILEA - 1) / TILEA)  // 391 binning blocks

typedef __bf16 bf16x8 __attribute__((ext_vector_type(8)));
typedef float f32x4 __attribute__((ext_vector_type(4)));

static __device__ __forceinline__ unsigned short f2bf(float f) {
    unsigned int u = __builtin_bit_cast(unsigned int, f);
    u += 0x7FFFu + ((u >> 16) & 1u);
    return (unsigned short)(u >> 16);
}
static __device__ __forceinline__ float b2f(unsigned short h) {
    unsigned int u = ((unsigned int)h) << 16;
    return __builtin_bit_cast(float, u);
}
static __device__ __forceinline__ float lo16(unsigned int w) {
    return __builtin_bit_cast(float, w << 16);
}
static __device__ __forceinline__ float hi16(unsigned int w) {
    return __builtin_bit_cast(float, w & 0xFFFF0000u);
}

// ---------- f32 -> bf16 convert (vector x4) ----------
__global__ void k_cvt_bf16(const float* __restrict__ in, unsigned short* __restrict__ out, int n) {
    int i = (blockIdx.x * blockDim.x + threadIdx.x) * 4;
    if (i + 3 < n) {
        float4 v = *(const float4*)(in + i);
        ushort4 o;
        o.x = f2bf(v.x); o.y = f2bf(v.y); o.z = f2bf(v.z); o.w = f2bf(v.w);
        *(ushort4*)(out + i) = o;
    } else {
        for (int t = 0; t < 4 && i + t < n; ++t) out[i + t] = f2bf(in[i + t]);
    }
}

// ---------- W[K,C] f32 -> Wt[C,K] bf16 ----------
__global__ void k_wT(const float* __restrict__ W, unsigned short* __restrict__ Wt, int K, int C) {
    int i = blockIdx.x * blockDim.x + threadIdx.x;
    if (i < K * C) {
        int k = i / C, c = i % C;
        Wt[c * K + k] = f2bf(W[i]);
    }
}

// ---------- CSR build ----------
__global__ void k_hist(const int* __restrict__ row, int* __restrict__ counts, int e) {
    int i = blockIdx.x * blockDim.x + threadIdx.x;
    if (i < e) atomicAdd(&counts[row[i]], 1);
}

__global__ void k_scan1(const int* __restrict__ counts, int* __restrict__ scanb,
                        int* __restrict__ parts, int n) {
    __shared__ int lds[256];
    int tid = threadIdx.x;
    int base = blockIdx.x * 1024 + tid * 4;
    int v[4]; int s = 0;
    for (int t = 0; t < 4; ++t) { v[t] = (base + t < n) ? counts[base + t] : 0; s += v[t]; }
    lds[tid] = s; __syncthreads();
    for (int off = 1; off < 256; off <<= 1) {
        int add = (tid >= off) ? lds[tid - off] : 0;
        __syncthreads();
        lds[tid] += add;
        __syncthreads();
    }
    int incl = lds[tid];
    int run = incl - s;
    for (int t = 0; t < 4; ++t) { run += v[t]; if (base + t < n) scanb[base + t] = run; }
    if (tid == 255) parts[blockIdx.x] = incl;
}

__global__ void k_scan2(int* __restrict__ parts, int np) {
    __shared__ int lds[128];
    int tid = threadIdx.x;
    int v = (tid < np) ? parts[tid] : 0;
    lds[tid] = v; __syncthreads();
    for (int off = 1; off < 128; off <<= 1) {
        int add = (tid >= off) ? lds[tid - off] : 0;
        __syncthreads();
        lds[tid] += add;
        __syncthreads();
    }
    parts[tid] = lds[tid] - v;  // exclusive
}

__global__ void k_scan3(const int* __restrict__ scanb, const int* __restrict__ parts,
                        int* __restrict__ rowp, int n) {
    int i = blockIdx.x * blockDim.x + threadIdx.x;
    if (i < n) {
        rowp[i + 1] = scanb[i] + parts[i >> 10];
        if (i == 0) rowp[0] = 0;
    }
}

// ---------- binning pass 1: per-(block,bucket) counts (LDS atomics only) ----------
// cmat layout column-major: cmat[b * NBLKA + blk]
__global__ __launch_bounds__(256) void k_cnt(const int* __restrict__ row, int* __restrict__ cmat, int e) {
    __shared__ int hist[NB];
    int tid = threadIdx.x;
    int tile0 = blockIdx.x * TILEA;
    for (int b = tid; b < NB; b += 256) hist[b] = 0;
    __syncthreads();
#pragma unroll 8
    for (int t = 0; t < TILEA / 256; ++t) {
        int i = tile0 + t * 256 + tid;
        if (i < e) atomicAdd(&hist[row[i] >> 8], 1);
    }
    __syncthreads();
    for (int b = tid; b < NB; b += 256) cmat[b * NBLKA + blockIdx.x] = hist[b];
}

// ---------- binning pass 2: exclusive scan of each bucket's column + rowp base ----------
__global__ __launch_bounds__(512) void k_cscan(int* __restrict__ cmat, const int* __restrict__ rowp) {
    __shared__ int lds[512];
    int b = blockIdx.x, tid = threadIdx.x;
    int v = (tid < NBLKA) ? cmat[b * NBLKA + tid] : 0;
    lds[tid] = v; __syncthreads();
    for (int off = 1; off < 512; off <<= 1) {
        int add = (tid >= off) ? lds[tid - off] : 0;
        __syncthreads();
        lds[tid] += add;
        __syncthreads();
    }
    if (tid < NBLKA) cmat[b * NBLKA + tid] = rowp[b << 8] + lds[tid] - v;  // exclusive + base
}

// ---------- binning pass 3: scatter to bucket-grouped tmp at scanned bases ----------
// record: high32 = val bits, low32 = col | (row&255)<<17   (col < 2^17)
__global__ __launch_bounds__(256) void k_scat2(const int* __restrict__ row, const int* __restrict__ col,
                                               const float* __restrict__ val, const int* __restrict__ cmat,
                                               unsigned long long* __restrict__ tmp, int e) {
    __shared__ int hist[NB];
    __shared__ int base[NB];
    int tid = threadIdx.x;
    int tile0 = blockIdx.x * TILEA;
    for (int b = tid; b < NB; b += 256) {
        base[b] = cmat[b * NBLKA + blockIdx.x];
        hist[b] = 0;
    }
    __syncthreads();
#pragma unroll 8
    for (int t = 0; t < TILEA / 256; ++t) {
        int i = tile0 + t * 256 + tid;
        if (i < e) {
            int r = row[i];
            int b = r >> 8;
            int rk = atomicAdd(&hist[b], 1);
            unsigned long long rec = ((unsigned long long)__builtin_bit_cast(unsigned int, val[i]) << 32)
                                   | (unsigned int)(col[i] | ((r & 255) << 17));
            tmp[base[b] + rk] = rec;
        }
    }
}

// ---------- binning pass 4: per-bucket fine sort to CSR via LDS cursors ----------
__global__ __launch_bounds__(256) void k_binB(const int* __restrict__ rowp,
                                              const unsigned long long* __restrict__ tmp,
                                              unsigned long long* __restrict__ pairs, int n) {
    __shared__ int cur[256];
    int tid = threadIdx.x;
    int r0 = blockIdx.x << 8;
    int s = rowp[r0];
    int eEnd = rowp[min(r0 + 256, n)];
    int rr = r0 + tid;
    cur[tid] = (rr < n) ? rowp[rr] : 0;  // rows >= n never occur
    __syncthreads();
    for (int i = s + tid; i < eEnd; i += 256) {
        unsigned long long rec = tmp[i];
        unsigned int w = (unsigned int)rec;
        int r = (w >> 17) & 255;
        int pos = atomicAdd(&cur[r], 1);
        pairs[pos] = (rec & 0xFFFFFFFF00000000ULL) | (unsigned long long)(w & 0x1FFFFu);
    }
}

// ---------- MFMA bf16 GEMM: C[M,256] = A[M,K] @ Bt[256,K]^T, optional bias+relu ----------
template <bool BR>
__global__ __launch_bounds__(256) void k_gemm(const unsigned short* __restrict__ A,
                                              const unsigned short* __restrict__ Bt,
                                              const float* __restrict__ bias,
                                              unsigned short* __restrict__ C,
                                              int M, int K) {
    int wave = threadIdx.x >> 6, lane = threadIdx.x & 63;
    int row0 = blockIdx.x * 64;
    int colBase = wave * 64;
    int hr = lane & 15, kg = lane >> 4;
    f32x4 acc[4][4];
#pragma unroll
    for (int r = 0; r < 4; ++r)
#pragma unroll
        for (int c = 0; c < 4; ++c) acc[r][c] = (f32x4){0.f, 0.f, 0.f, 0.f};

    for (int k0 = 0; k0 < K; k0 += 32) {
        int kk = k0 + kg * 8;
        bf16x8 af[4], bf_[4];
#pragma unroll
        for (int r = 0; r < 4; ++r) {
            int ar = row0 + r * 16 + hr;
            if (ar >= M) ar = M - 1;
            af[r] = *(const bf16x8*)(A + (size_t)ar * K + kk);
        }
#pragma unroll
        for (int c = 0; c < 4; ++c) {
            int bc = colBase + c * 16 + hr;
            bf_[c] = *(const bf16x8*)(Bt + (size_t)bc * K + kk);
        }
#pragma unroll
        for (int r = 0; r < 4; ++r)
#pragma unroll
            for (int c = 0; c < 4; ++c)
                acc[r][c] = __builtin_amdgcn_mfma_f32_16x16x32_bf16(af[r], bf_[c], acc[r][c], 0, 0, 0);
    }
    // C/D layout: col = lane&15, row = (lane>>4)*4 + reg
#pragma unroll
    for (int r = 0; r < 4; ++r)
#pragma unroll
        for (int c = 0; c < 4; ++c) {
            int col = colBase + c * 16 + hr;
            float bv = BR ? bias[col] : 0.f;
#pragma unroll
            for (int i = 0; i < 4; ++i) {
                int rr = row0 + r * 16 + kg * 4 + i;
                float v = acc[r][c][i];
                if (BR) v = fmaxf(v + bv, 0.f);
                if (rr < M) C[(size_t)rr * 256 + col] = f2bf(v);
            }
        }
}

// ---------- SpMM D=256: out[row] = relu(sum val*S[col] + bias) ----------
// 2 edges per gather instruction: half-wave (32 lanes x 16B = full 512B row) per edge.
__global__ __launch_bounds__(256) void k_spmm256(const int* __restrict__ rowp,
                                                 const unsigned long long* __restrict__ pairs,
                                                 const unsigned short* __restrict__ S,
                                                 const float* __restrict__ bias,
                                                 unsigned short* __restrict__ Hout, int n) {
    int lane = threadIdx.x & 63;
    int row = blockIdx.x * 4 + (threadIdx.x >> 6);
    if (row >= n) return;
    int s = rowp[row], e = rowp[row + 1];
    int half = lane >> 5;          // 0/1: which edge of the pair
    int f = (lane & 31) * 8;       // 8 features (16B) per lane
    float a0 = 0.f, a1 = 0.f, a2 = 0.f, a3 = 0.f, a4 = 0.f, a5 = 0.f, a6 = 0.f, a7 = 0.f;
#pragma unroll 4
    for (int i = s; i < e; i += 2) {
        int idx = i + half;
        bool act = idx < e;
        unsigned long long p = pairs[act ? idx : i];
        unsigned int c = (unsigned int)p;
        float v = __builtin_bit_cast(float, (unsigned int)(p >> 32));
        if (!act) v = 0.f;
        uint4 t = *(const uint4*)(S + (size_t)c * 256 + f);
        a0 += v * lo16(t.x); a1 += v * hi16(t.x);
        a2 += v * lo16(t.y); a3 += v * hi16(t.y);
        a4 += v * lo16(t.z); a5 += v * hi16(t.z);
        a6 += v * lo16(t.w); a7 += v * hi16(t.w);
    }
    // merge the two half-wave partial sums
    a0 += __shfl_xor(a0, 32); a1 += __shfl_xor(a1, 32);
    a2 += __shfl_xor(a2, 32); a3 += __shfl_xor(a3, 32);
    a4 += __shfl_xor(a4, 32); a5 += __shfl_xor(a5, 32);
    a6 += __shfl_xor(a6, 32); a7 += __shfl_xor(a7, 32);
    if (half == 0) {
        float4 b0 = *(const float4*)(bias + f);
        float4 b1 = *(const float4*)(bias + f + 4);
        a0 = fmaxf(a0 + b0.x, 0.f); a1 = fmaxf(a1 + b0.y, 0.f);
        a2 = fmaxf(a2 + b0.z, 0.f); a3 = fmaxf(a3 + b0.w, 0.f);
        a4 = fmaxf(a4 + b1.x, 0.f); a5 = fmaxf(a5 + b1.y, 0.f);
        a6 = fmaxf(a6 + b1.z, 0.f); a7 = fmaxf(a7 + b1.w, 0.f);
        uint4 o;
        o.x = (unsigned int)f2bf(a0) | ((unsigned int)f2bf(a1) << 16);
        o.y = (unsigned int)f2bf(a2) | ((unsigned int)f2bf(a3) << 16);
        o.z = (unsigned int)f2bf(a4) | ((unsigned int)f2bf(a5) << 16);
        o.w = (unsigned int)f2bf(a6) | ((unsigned int)f2bf(a7) << 16);
        *(uint4*)(Hout + (size_t)row * 256 + f) = o;
    }
}

// ---------- SpMM D=128, no bias/relu: 4 edges per gather instruction ----------
__global__ __launch_bounds__(256) void k_spmm128(const int* __restrict__ rowp,
                                                 const unsigned long long* __restrict__ pairs,
                                                 const unsigned short* __restrict__ X,
                                                 unsigned short* __restrict__ Out, int n) {
    int lane = threadIdx.x & 63;
    int row = blockIdx.x * 4 + (threadIdx.x >> 6);
    if (row >= n) return;
    int s = rowp[row], e = rowp[row + 1];
    int q = lane >> 4;             // 0..3: which edge of the quad
    int f = (lane & 15) * 8;       // 8 features (16B) per lane
    float a0 = 0.f, a1 = 0.f, a2 = 0.f, a3 = 0.f, a4 = 0.f, a5 = 0.f, a6 = 0.f, a7 = 0.f;
#pragma unroll 4
    for (int i = s; i < e; i += 4) {
        int idx = i + q;
        bool act = idx < e;
        unsigned long long p = pairs[act ? idx : i];
        unsigned int c = (unsigned int)p;
        float v = __builtin_bit_cast(float, (unsigned int)(p >> 32));
        if (!act) v = 0.f;
        uint4 t = *(const uint4*)(X + (size_t)c * 128 + f);
        a0 += v * lo16(t.x); a1 += v * hi16(t.x);
        a2 += v * lo16(t.y); a3 += v * hi16(t.y);
        a4 += v * lo16(t.z); a5 += v * hi16(t.z);
        a6 += v * lo16(t.w); a7 += v * hi16(t.w);
    }
    a0 += __shfl_xor(a0, 16); a1 += __shfl_xor(a1, 16);
    a2 += __shfl_xor(a2, 16); a3 += __shfl_xor(a3, 16);
    a4 += __shfl_xor(a4, 16); a5 += __shfl_xor(a5, 16);
    a6 += __shfl_xor(a6, 16); a7 += __shfl_xor(a7, 16);
    a0 += __shfl_xor(a0, 32); a1 += __shfl_xor(a1, 32);
    a2 += __shfl_xor(a2, 32); a3 += __shfl_xor(a3, 32);
    a4 += __shfl_xor(a4, 32); a5 += __shfl_xor(a5, 32);
    a6 += __shfl_xor(a6, 32); a7 += __shfl_xor(a7, 32);
    if (lane < 16) {
        uint4 o;
        o.x = (unsigned int)f2bf(a0) | ((unsigned int)f2bf(a1) << 16);
        o.y = (unsigned int)f2bf(a2) | ((unsigned int)f2bf(a3) << 16);
        o.z = (unsigned int)f2bf(a4) | ((unsigned int)f2bf(a5) << 16);
        o.w = (unsigned int)f2bf(a6) | ((unsigned int)f2bf(a7) << 16);
        *(uint4*)(Out + (size_t)row * 128 + f) = o;
    }
}

// ---------- FC + log_softmax: 16 lanes per node ----------
__global__ __launch_bounds__(256) void k_fc_lsm(const unsigned short* __restrict__ H,
                                                const float* __restrict__ Wf,
                                                const float* __restrict__ bf,
                                                float* __restrict__ out, int n) {
    int lane = threadIdx.x & 63;
    int wave = threadIdx.x >> 6;
    int sub = lane >> 4, j = lane & 15;
    int node = (blockIdx.x * 4 + wave) * 4 + sub;
    bool valid = node < n;
    int nd = valid ? node : (n - 1);
    float acc = 0.f;
    for (int f0 = 0; f0 < NH; f0 += 8) {
        union { uint4 u; unsigned short s[8]; } h;
        h.u = *(const uint4*)(H + (size_t)nd * NH + f0);
#pragma unroll
        for (int t = 0; t < 8; ++t) acc += b2f(h.s[t]) * Wf[(f0 + t) * NC + j];
    }
    acc += bf[j];
    float mx = acc;
    for (int m = 1; m < 16; m <<= 1) mx = fmaxf(mx, __shfl_xor(mx, m, 16));
    float sm = __expf(acc - mx);
    for (int m = 1; m < 16; m <<= 1) sm += __shfl_xor(sm, m, 16);
    float res = acc - mx - __logf(sm);
    if (valid) out[(size_t)node * NC + j] = res;
}

extern "C" void kernel_launch(void* const* d_in, const int* in_sizes, int n_in,
                              void* d_out, int out_size, void* d_ws, size_t ws_size,
                              hipStream_t stream) {
    const float* x      = (const float*)d_in[0];
    const float* adjval = (const float*)d_in[1];
    const float* w1 = (const float*)d_in[2];  const float* b1 = (const float*)d_in[3];
    const float* w2 = (const float*)d_in[4];  const float* b2 = (const float*)d_in[5];
    const float* w3 = (const float*)d_in[6];  const float* b3 = (const float*)d_in[7];
    const float* w4 = (const float*)d_in[8];  const float* b4 = (const float*)d_in[9];
    const float* fcw = (const float*)d_in[10]; const float* fcb = (const float*)d_in[11];
    const int* arow = (const int*)d_in[12];
    const int* acol = (const int*)d_in[13];
    float* out = (float*)d_out;

    char* ws = (char*)d_ws;
    size_t off = 0;
    auto alloc = [&](size_t bytes) { size_t o = off; off += (bytes + 255) & ~(size_t)255; return o; };

    unsigned short* xb  = (unsigned short*)(ws + alloc((size_t)NN * NF * 2));
    unsigned short* Sb  = (unsigned short*)(ws + alloc((size_t)NN * NH * 2));  // also holds Ax [N,128] for layer 1
    unsigned short* H1  = (unsigned short*)(ws + alloc((size_t)NN * NH * 2));
    unsigned short* H2  = (unsigned short*)(ws + alloc((size_t)NN * NH * 2));
    unsigned short* Wt1 = (unsigned short*)(ws + alloc((size_t)NH * NF * 2));
    unsigned short* Wt2 = (unsigned short*)(ws + alloc((size_t)NH * NH * 2));
    unsigned short* Wt3 = (unsigned short*)(ws + alloc((size_t)NH * NH * 2));
    unsigned short* Wt4 = (unsigned short*)(ws + alloc((size_t)NH * NH * 2));
    int*   counts = (int*)(ws + alloc((size_t)NN * 4));
    int*   scanb  = (int*)(ws + alloc((size_t)NN * 4));
    int*   parts  = (int*)(ws + alloc(128 * 4));
    int*   rowp   = (int*)(ws + alloc(((size_t)NN + 1) * 4));
    int*   cmat   = (int*)(ws + alloc((size_t)NB * NBLKA * 4));
    unsigned long long* pairs = (unsigned long long*)(ws + alloc((size_t)EE * 8));
    // tmp for binning reuses H2 (dead until layer 2; 51.2MB >= 25.6MB)
    unsigned long long* tmp = (unsigned long long*)H2;

    // --- input conversions ---
    k_cvt_bf16<<<(NN * NF / 4 + 255) / 256, 256, 0, stream>>>(x, xb, NN * NF);
    k_wT<<<(NF * NH + 255) / 256, 256, 0, stream>>>(w1, Wt1, NF, NH);
    k_wT<<<(NH * NH + 255) / 256, 256, 0, stream>>>(w2, Wt2, NH, NH);
    k_wT<<<(NH * NH + 255) / 256, 256, 0, stream>>>(w3, Wt3, NH, NH);
    k_wT<<<(NH * NH + 255) / 256, 256, 0, stream>>>(w4, Wt4, NH, NH);

    // --- CSR build ---
    hipMemsetAsync(counts, 0, (size_t)NN * 4, stream);
    k_hist<<<(EE + 255) / 256, 256, 0, stream>>>(arow, counts, EE);
    int nscan = (NN + 1023) / 1024;  // 98
    k_scan1<<<nscan, 256, 0, stream>>>(counts, scanb, parts, NN);
    k_scan2<<<1, 128, 0, stream>>>(parts, nscan);
    k_scan3<<<(NN + 255) / 256, 256, 0, stream>>>(scanb, parts, rowp, NN);
    // atomic-free counting-sort binning: count -> column-scan -> scatter -> fine sort
    k_cnt<<<NBLKA, 256, 0, stream>>>(arow, cmat, EE);
    k_cscan<<<NB, 512, 0, stream>>>(cmat, rowp);
    k_scat2<<<NBLKA, 256, 0, stream>>>(arow, acol, adjval, cmat, tmp, EE);
    k_binB<<<NB, 256, 0, stream>>>(rowp, tmp, pairs, NN);

    int gGemm = (NN + 63) / 64;     // 1563
    int gSpmm = (NN + 3) / 4;       // 25000
    // --- layer 1 (reordered: (A@x)@W1, gathers 128 feats instead of 256) ---
    k_spmm128<<<gSpmm, 256, 0, stream>>>(rowp, pairs, xb, Sb, NN);
    k_gemm<true><<<gGemm, 256, 0, stream>>>(Sb, Wt1, b1, H1, NN, NF);
    // --- layer 2 ---
    k_gemm<false><<<gGemm, 256, 0, stream>>>(H1, Wt2, nullptr, Sb, NN, NH);
    k_spmm256<<<gSpmm, 256, 0, stream>>>(rowp, pairs, Sb, b2, H2, NN);
    // --- layer 3 ---
    k_gemm<false><<<gGemm, 256, 0, stream>>>(H2, Wt3, nullptr, Sb, NN, NH);
    k_spmm256<<<gSpmm, 256, 0, stream>>>(rowp, pairs, Sb, b3, H1, NN);
    // --- layer 4 ---
    k_gemm<false><<<gGemm, 256, 0, stream>>>(H1, Wt4, nullptr, Sb, NN, NH);
    k_spmm256<<<gSpmm, 256, 0, stream>>>(rowp, pairs, Sb, b4, H2, NN);
    // --- FC + log_softmax ---
    k_fc_lsm<<<(NN + 15) / 16, 256, 0, stream>>>(H2, fcw, fcb, out, NN);
}

// Round 5
// 1115.957 us; speedup vs baseline: 1.3696x; 1.2699x over previous
//
#include <hip/hip_runtime.h>
#include <hip/hip_bf16.h>

#define NN 100000
#define EE 3200000
#define NF 128
#define NH 256
#define NC 16
#define NB ((NN + 255) >> 8)          // 391 coarse buckets of 256 rows
#define TILEA 8192
#define NBLKA ((EE + TILEA - 1) / TILEA)  // 391 binning blocks

typedef __bf16 bf16x8 __attribute__((ext_vector_type(8)));
typedef float f32x4 __attribute__((ext_vector_type(4)));
typedef float f32x2 __attribute__((ext_vector_type(2)));

static __device__ __forceinline__ unsigned short f2bf(float f) {
    unsigned int u = __builtin_bit_cast(unsigned int, f);
    u += 0x7FFFu + ((u >> 16) & 1u);
    return (unsigned short)(u >> 16);
}
static __device__ __forceinline__ float b2f(unsigned short h) {
    unsigned int u = ((unsigned int)h) << 16;
    return __builtin_bit_cast(float, u);
}
static __device__ __forceinline__ unsigned char f2fp8(float v) {
    return (unsigned char)(__builtin_amdgcn_cvt_pk_fp8_f32(v, v, 0, false) & 0xFF);
}

// ---------- x f32 -> fp8 convert (vector x4) ----------
__global__ void k_cvt_fp8(const float* __restrict__ in, unsigned char* __restrict__ out, int n) {
    int i = (blockIdx.x * blockDim.x + threadIdx.x) * 4;
    if (i + 3 < n) {
        float4 v = *(const float4*)(in + i);
        int r = __builtin_amdgcn_cvt_pk_fp8_f32(v.x, v.y, 0, false);
        r = __builtin_amdgcn_cvt_pk_fp8_f32(v.z, v.w, r, true);
        *(unsigned int*)(out + i) = (unsigned int)r;
    } else {
        for (int t = 0; t < 4 && i + t < n; ++t) out[i + t] = f2fp8(in[i + t]);
    }
}

// ---------- W[K,C] f32 -> Wt[C,K] bf16 ----------
__global__ void k_wT(const float* __restrict__ W, unsigned short* __restrict__ Wt, int K, int C) {
    int i = blockIdx.x * blockDim.x + threadIdx.x;
    if (i < K * C) {
        int k = i / C, c = i % C;
        Wt[c * K + k] = f2bf(W[i]);
    }
}

// ---------- CSR build ----------
__global__ void k_hist(const int* __restrict__ row, int* __restrict__ counts, int e) {
    int i = blockIdx.x * blockDim.x + threadIdx.x;
    if (i < e) atomicAdd(&counts[row[i]], 1);
}

__global__ void k_scan1(const int* __restrict__ counts, int* __restrict__ scanb,
                        int* __restrict__ parts, int n) {
    __shared__ int lds[256];
    int tid = threadIdx.x;
    int base = blockIdx.x * 1024 + tid * 4;
    int v[4]; int s = 0;
    for (int t = 0; t < 4; ++t) { v[t] = (base + t < n) ? counts[base + t] : 0; s += v[t]; }
    lds[tid] = s; __syncthreads();
    for (int off = 1; off < 256; off <<= 1) {
        int add = (tid >= off) ? lds[tid - off] : 0;
        __syncthreads();
        lds[tid] += add;
        __syncthreads();
    }
    int incl = lds[tid];
    int run = incl - s;
    for (int t = 0; t < 4; ++t) { run += v[t]; if (base + t < n) scanb[base + t] = run; }
    if (tid == 255) parts[blockIdx.x] = incl;
}

__global__ void k_scan2(int* __restrict__ parts, int np) {
    __shared__ int lds[128];
    int tid = threadIdx.x;
    int v = (tid < np) ? parts[tid] : 0;
    lds[tid] = v; __syncthreads();
    for (int off = 1; off < 128; off <<= 1) {
        int add = (tid >= off) ? lds[tid - off] : 0;
        __syncthreads();
        lds[tid] += add;
        __syncthreads();
    }
    parts[tid] = lds[tid] - v;  // exclusive
}

__global__ void k_scan3(const int* __restrict__ scanb, const int* __restrict__ parts,
                        int* __restrict__ rowp, int n) {
    int i = blockIdx.x * blockDim.x + threadIdx.x;
    if (i < n) {
        rowp[i + 1] = scanb[i] + parts[i >> 10];
        if (i == 0) rowp[0] = 0;
    }
}

// ---------- binning pass 1: per-(block,bucket) counts (LDS atomics only) ----------
// cmat layout column-major: cmat[b * NBLKA + blk]
__global__ __launch_bounds__(256) void k_cnt(const int* __restrict__ row, int* __restrict__ cmat, int e) {
    __shared__ int hist[NB];
    int tid = threadIdx.x;
    int tile0 = blockIdx.x * TILEA;
    for (int b = tid; b < NB; b += 256) hist[b] = 0;
    __syncthreads();
#pragma unroll 8
    for (int t = 0; t < TILEA / 256; ++t) {
        int i = tile0 + t * 256 + tid;
        if (i < e) atomicAdd(&hist[row[i] >> 8], 1);
    }
    __syncthreads();
    for (int b = tid; b < NB; b += 256) cmat[b * NBLKA + blockIdx.x] = hist[b];
}

// ---------- binning pass 2: exclusive scan of each bucket's column + rowp base ----------
__global__ __launch_bounds__(512) void k_cscan(int* __restrict__ cmat, const int* __restrict__ rowp) {
    __shared__ int lds[512];
    int b = blockIdx.x, tid = threadIdx.x;
    int v = (tid < NBLKA) ? cmat[b * NBLKA + tid] : 0;
    lds[tid] = v; __syncthreads();
    for (int off = 1; off < 512; off <<= 1) {
        int add = (tid >= off) ? lds[tid - off] : 0;
        __syncthreads();
        lds[tid] += add;
        __syncthreads();
    }
    if (tid < NBLKA) cmat[b * NBLKA + tid] = rowp[b << 8] + lds[tid] - v;  // exclusive + base
}

// ---------- binning pass 3: scatter to bucket-grouped tmp at scanned bases ----------
// record: high32 = val bits, low32 = col | (row&255)<<17   (col < 2^17)
__global__ __launch_bounds__(256) void k_scat2(const int* __restrict__ row, const int* __restrict__ col,
                                               const float* __restrict__ val, const int* __restrict__ cmat,
                                               unsigned long long* __restrict__ tmp, int e) {
    __shared__ int hist[NB];
    __shared__ int base[NB];
    int tid = threadIdx.x;
    int tile0 = blockIdx.x * TILEA;
    for (int b = tid; b < NB; b += 256) {
        base[b] = cmat[b * NBLKA + blockIdx.x];
        hist[b] = 0;
    }
    __syncthreads();
#pragma unroll 8
    for (int t = 0; t < TILEA / 256; ++t) {
        int i = tile0 + t * 256 + tid;
        if (i < e) {
            int r = row[i];
            int b = r >> 8;
            int rk = atomicAdd(&hist[b], 1);
            unsigned long long rec = ((unsigned long long)__builtin_bit_cast(unsigned int, val[i]) << 32)
                                   | (unsigned int)(col[i] | ((r & 255) << 17));
            tmp[base[b] + rk] = rec;
        }
    }
}

// ---------- binning pass 4: per-bucket fine sort to CSR via LDS cursors ----------
__global__ __launch_bounds__(256) void k_binB(const int* __restrict__ rowp,
                                              const unsigned long long* __restrict__ tmp,
                                              unsigned long long* __restrict__ pairs, int n) {
    __shared__ int cur[256];
    int tid = threadIdx.x;
    int r0 = blockIdx.x << 8;
    int s = rowp[r0];
    int eEnd = rowp[min(r0 + 256, n)];
    int rr = r0 + tid;
    cur[tid] = (rr < n) ? rowp[rr] : 0;  // rows >= n never occur
    __syncthreads();
    for (int i = s + tid; i < eEnd; i += 256) {
        unsigned long long rec = tmp[i];
        unsigned int w = (unsigned int)rec;
        int r = (w >> 17) & 255;
        int pos = atomicAdd(&cur[r], 1);
        pairs[pos] = (rec & 0xFFFFFFFF00000000ULL) | (unsigned long long)(w & 0x1FFFFu);
    }
}

// ---------- MFMA bf16 GEMM: C[M,256] = A[M,K] @ Bt[256,K]^T ----------
// BR: +bias+relu, bf16 output. F8: raw output quantized to fp8 (gather source for SpMM).
template <bool BR, bool F8>
__global__ __launch_bounds__(256) void k_gemm(const unsigned short* __restrict__ A,
                                              const unsigned short* __restrict__ Bt,
                                              const float* __restrict__ bias,
                                              unsigned short* __restrict__ C,
                                              unsigned char* __restrict__ C8,
                                              int M, int K) {
    int wave = threadIdx.x >> 6, lane = threadIdx.x & 63;
    int row0 = blockIdx.x * 64;
    int colBase = wave * 64;
    int hr = lane & 15, kg = lane >> 4;
    f32x4 acc[4][4];
#pragma unroll
    for (int r = 0; r < 4; ++r)
#pragma unroll
        for (int c = 0; c < 4; ++c) acc[r][c] = (f32x4){0.f, 0.f, 0.f, 0.f};

    for (int k0 = 0; k0 < K; k0 += 32) {
        int kk = k0 + kg * 8;
        bf16x8 af[4], bf_[4];
#pragma unroll
        for (int r = 0; r < 4; ++r) {
            int ar = row0 + r * 16 + hr;
            if (ar >= M) ar = M - 1;
            af[r] = *(const bf16x8*)(A + (size_t)ar * K + kk);
        }
#pragma unroll
        for (int c = 0; c < 4; ++c) {
            int bc = colBase + c * 16 + hr;
            bf_[c] = *(const bf16x8*)(Bt + (size_t)bc * K + kk);
        }
#pragma unroll
        for (int r = 0; r < 4; ++r)
#pragma unroll
            for (int c = 0; c < 4; ++c)
                acc[r][c] = __builtin_amdgcn_mfma_f32_16x16x32_bf16(af[r], bf_[c], acc[r][c], 0, 0, 0);
    }
    // C/D layout: col = lane&15, row = (lane>>4)*4 + reg
#pragma unroll
    for (int r = 0; r < 4; ++r)
#pragma unroll
        for (int c = 0; c < 4; ++c) {
            int col = colBase + c * 16 + hr;
            float bv = BR ? bias[col] : 0.f;
#pragma unroll
            for (int i = 0; i < 4; ++i) {
                int rr = row0 + r * 16 + kg * 4 + i;
                float v = acc[r][c][i];
                if (BR) v = fmaxf(v + bv, 0.f);
                if (rr < M) {
                    if (F8) C8[(size_t)rr * 256 + col] = f2fp8(v);
                    else    C[(size_t)rr * 256 + col] = f2bf(v);
                }
            }
        }
}

// ---------- SpMM D=256 over fp8 source: out[row] = relu(sum val*S[col] + bias), bf16 out ----------
__global__ __launch_bounds__(256) void k_spmm256(const int* __restrict__ rowp,
                                                 const unsigned long long* __restrict__ pairs,
                                                 const unsigned char* __restrict__ S,
                                                 const float* __restrict__ bias,
                                                 unsigned short* __restrict__ Hout, int n) {
    int lane = threadIdx.x & 63;
    int row = blockIdx.x * 4 + (threadIdx.x >> 6);
    if (row >= n) return;
    int s = rowp[row], e = rowp[row + 1];
    int f = lane * 4;   // 4 feats per lane, 64 lanes x 4B = full 256B fp8 row
    float a0 = 0.f, a1 = 0.f, a2 = 0.f, a3 = 0.f;
#pragma unroll 8
    for (int i = s; i < e; ++i) {
        unsigned long long p = pairs[i];
        unsigned int c = (unsigned int)p;
        float v = __builtin_bit_cast(float, (unsigned int)(p >> 32));
        int w = *(const int*)(S + (size_t)c * 256 + f);
        f32x2 dlo = __builtin_amdgcn_cvt_pk_f32_fp8(w, false);
        f32x2 dhi = __builtin_amdgcn_cvt_pk_f32_fp8(w, true);
        a0 += v * dlo.x; a1 += v * dlo.y; a2 += v * dhi.x; a3 += v * dhi.y;
    }
    float4 bv = *(const float4*)(bias + f);
    a0 = fmaxf(a0 + bv.x, 0.f);
    a1 = fmaxf(a1 + bv.y, 0.f);
    a2 = fmaxf(a2 + bv.z, 0.f);
    a3 = fmaxf(a3 + bv.w, 0.f);
    ushort4 o; o.x = f2bf(a0); o.y = f2bf(a1); o.z = f2bf(a2); o.w = f2bf(a3);
    *(ushort4*)(Hout + (size_t)row * 256 + f) = o;
}

// ---------- SpMM D=128 over fp8 x, no bias/relu: out = sum val*X[col], bf16 out ----------
__global__ __launch_bounds__(256) void k_spmm128(const int* __restrict__ rowp,
                                                 const unsigned long long* __restrict__ pairs,
                                                 const unsigned char* __restrict__ X,
                                                 unsigned short* __restrict__ Out, int n) {
    int lane = threadIdx.x & 63;
    int row = blockIdx.x * 4 + (threadIdx.x >> 6);
    if (row >= n) return;
    int s = rowp[row], e = rowp[row + 1];
    int f = lane * 2;   // 2 feats per lane, 64 lanes x 2B = full 128B fp8 row
    float a0 = 0.f, a1 = 0.f;
#pragma unroll 8
    for (int i = s; i < e; ++i) {
        unsigned long long p = pairs[i];
        unsigned int c = (unsigned int)p;
        float v = __builtin_bit_cast(float, (unsigned int)(p >> 32));
        int w = (int)*(const unsigned short*)(X + (size_t)c * 128 + f);
        f32x2 d = __builtin_amdgcn_cvt_pk_f32_fp8(w, false);
        a0 += v * d.x; a1 += v * d.y;
    }
    ushort2 o; o.x = f2bf(a0); o.y = f2bf(a1);
    *(ushort2*)(Out + (size_t)row * 128 + f) = o;
}

// ---------- FC + log_softmax: 16 lanes per node ----------
__global__ __launch_bounds__(256) void k_fc_lsm(const unsigned short* __restrict__ H,
                                                const float* __restrict__ Wf,
                                                const float* __restrict__ bf,
                                                float* __restrict__ out, int n) {
    int lane = threadIdx.x & 63;
    int wave = threadIdx.x >> 6;
    int sub = lane >> 4, j = lane & 15;
    int node = (blockIdx.x * 4 + wave) * 4 + sub;
    bool valid = node < n;
    int nd = valid ? node : (n - 1);
    float acc = 0.f;
    for (int f0 = 0; f0 < NH; f0 += 8) {
        union { uint4 u; unsigned short s[8]; } h;
        h.u = *(const uint4*)(H + (size_t)nd * NH + f0);
#pragma unroll
        for (int t = 0; t < 8; ++t) acc += b2f(h.s[t]) * Wf[(f0 + t) * NC + j];
    }
    acc += bf[j];
    float mx = acc;
    for (int m = 1; m < 16; m <<= 1) mx = fmaxf(mx, __shfl_xor(mx, m, 16));
    float sm = __expf(acc - mx);
    for (int m = 1; m < 16; m <<= 1) sm += __shfl_xor(sm, m, 16);
    float res = acc - mx - __logf(sm);
    if (valid) out[(size_t)node * NC + j] = res;
}

extern "C" void kernel_launch(void* const* d_in, const int* in_sizes, int n_in,
                              void* d_out, int out_size, void* d_ws, size_t ws_size,
                              hipStream_t stream) {
    const float* x      = (const float*)d_in[0];
    const float* adjval = (const float*)d_in[1];
    const float* w1 = (const float*)d_in[2];  const float* b1 = (const float*)d_in[3];
    const float* w2 = (const float*)d_in[4];  const float* b2 = (const float*)d_in[5];
    const float* w3 = (const float*)d_in[6];  const float* b3 = (const float*)d_in[7];
    const float* w4 = (const float*)d_in[8];  const float* b4 = (const float*)d_in[9];
    const float* fcw = (const float*)d_in[10]; const float* fcb = (const float*)d_in[11];
    const int* arow = (const int*)d_in[12];
    const int* acol = (const int*)d_in[13];
    float* out = (float*)d_out;

    char* ws = (char*)d_ws;
    size_t off = 0;
    auto alloc = [&](size_t bytes) { size_t o = off; off += (bytes + 255) & ~(size_t)255; return o; };

    unsigned char*  xb  = (unsigned char*)(ws + alloc((size_t)NN * NF));       // fp8 x
    unsigned short* Sb  = (unsigned short*)(ws + alloc((size_t)NN * NH * 2));  // layer-1 Ax bf16 / fp8 S (25.6MB each)
    unsigned short* H1  = (unsigned short*)(ws + alloc((size_t)NN * NH * 2));
    unsigned short* H2  = (unsigned short*)(ws + alloc((size_t)NN * NH * 2));
    unsigned short* Wt1 = (unsigned short*)(ws + alloc((size_t)NH * NF * 2));
    unsigned short* Wt2 = (unsigned short*)(ws + alloc((size_t)NH * NH * 2));
    unsigned short* Wt3 = (unsigned short*)(ws + alloc((size_t)NH * NH * 2));
    unsigned short* Wt4 = (unsigned short*)(ws + alloc((size_t)NH * NH * 2));
    int*   counts = (int*)(ws + alloc((size_t)NN * 4));
    int*   scanb  = (int*)(ws + alloc((size_t)NN * 4));
    int*   parts  = (int*)(ws + alloc(128 * 4));
    int*   rowp   = (int*)(ws + alloc(((size_t)NN + 1) * 4));
    int*   cmat   = (int*)(ws + alloc((size_t)NB * NBLKA * 4));
    unsigned long long* pairs = (unsigned long long*)(ws + alloc((size_t)EE * 8));
    // tmp for binning reuses H2 (dead until layer 2; 51.2MB >= 25.6MB)
    unsigned long long* tmp = (unsigned long long*)H2;
    unsigned char* S8 = (unsigned char*)Sb;   // fp8 view of Sb for layers 2-4

    // --- input conversions ---
    k_cvt_fp8<<<(NN * NF / 4 + 255) / 256, 256, 0, stream>>>(x, xb, NN * NF);
    k_wT<<<(NF * NH + 255) / 256, 256, 0, stream>>>(w1, Wt1, NF, NH);
    k_wT<<<(NH * NH + 255) / 256, 256, 0, stream>>>(w2, Wt2, NH, NH);
    k_wT<<<(NH * NH + 255) / 256, 256, 0, stream>>>(w3, Wt3, NH, NH);
    k_wT<<<(NH * NH + 255) / 256, 256, 0, stream>>>(w4, Wt4, NH, NH);

    // --- CSR build ---
    hipMemsetAsync(counts, 0, (size_t)NN * 4, stream);
    k_hist<<<(EE + 255) / 256, 256, 0, stream>>>(arow, counts, EE);
    int nscan = (NN + 1023) / 1024;  // 98
    k_scan1<<<nscan, 256, 0, stream>>>(counts, scanb, parts, NN);
    k_scan2<<<1, 128, 0, stream>>>(parts, nscan);
    k_scan3<<<(NN + 255) / 256, 256, 0, stream>>>(scanb, parts, rowp, NN);
    // atomic-free counting-sort binning: count -> column-scan -> scatter -> fine sort
    k_cnt<<<NBLKA, 256, 0, stream>>>(arow, cmat, EE);
    k_cscan<<<NB, 512, 0, stream>>>(cmat, rowp);
    k_scat2<<<NBLKA, 256, 0, stream>>>(arow, acol, adjval, cmat, tmp, EE);
    k_binB<<<NB, 256, 0, stream>>>(rowp, tmp, pairs, NN);

    int gGemm = (NN + 63) / 64;     // 1563
    int gSpmm = (NN + 3) / 4;       // 25000
    // --- layer 1 (reordered: (A@x)@W1, gathers fp8 x) ---
    k_spmm128<<<gSpmm, 256, 0, stream>>>(rowp, pairs, xb, Sb, NN);
    k_gemm<true, false><<<gGemm, 256, 0, stream>>>(Sb, Wt1, b1, H1, nullptr, NN, NF);
    // --- layer 2 (GEMM emits fp8 S, SpMM gathers fp8) ---
    k_gemm<false, true><<<gGemm, 256, 0, stream>>>(H1, Wt2, nullptr, nullptr, S8, NN, NH);
    k_spmm256<<<gSpmm, 256, 0, stream>>>(rowp, pairs, S8, b2, H2, NN);
    // --- layer 3 ---
    k_gemm<false, true><<<gGemm, 256, 0, stream>>>(H2, Wt3, nullptr, nullptr, S8, NN, NH);
    k_spmm256<<<gSpmm, 256, 0, stream>>>(rowp, pairs, S8, b3, H1, NN);
    // --- layer 4 ---
    k_gemm<false, true><<<gGemm, 256, 0, stream>>>(H1, Wt4, nullptr, nullptr, S8, NN, NH);
    k_spmm256<<<gSpmm, 256, 0, stream>>>(rowp, pairs, S8, b4, H2, NN);
    // --- FC + log_softmax ---
    k_fc_lsm<<<(NN + 15) / 16, 256, 0, stream>>>(H2, fcw, fcb, out, NN);
}

// Round 6
// 995.587 us; speedup vs baseline: 1.5352x; 1.1209x over previous
//
#include <hip/hip_runtime.h>
#include <hip/hip_bf16.h>

#define NN 100000
#define EE 3200000
#define NF 128
#define NH 256
#define NC 16
#define NB ((NN + 255) >> 8)          // 391 coarse buckets of 256 rows
#define TILEA 8192
#define NBLKA ((EE + TILEA - 1) / TILEA)  // 391 binning blocks

typedef __bf16 bf16x8 __attribute__((ext_vector_type(8)));
typedef float f32x4 __attribute__((ext_vector_type(4)));
typedef float f32x2 __attribute__((ext_vector_type(2)));

static __device__ __forceinline__ unsigned short f2bf(float f) {
    unsigned int u = __builtin_bit_cast(unsigned int, f);
    u += 0x7FFFu + ((u >> 16) & 1u);
    return (unsigned short)(u >> 16);
}
static __device__ __forceinline__ float b2f(unsigned short h) {
    unsigned int u = ((unsigned int)h) << 16;
    return __builtin_bit_cast(float, u);
}
static __device__ __forceinline__ unsigned char f2fp8(float v) {
    return (unsigned char)(__builtin_amdgcn_cvt_pk_fp8_f32(v, v, 0, false) & 0xFF);
}

// ---------- x f32 -> fp8 convert (vector x4) ----------
__global__ void k_cvt_fp8(const float* __restrict__ in, unsigned char* __restrict__ out, int n) {
    int i = (blockIdx.x * blockDim.x + threadIdx.x) * 4;
    if (i + 3 < n) {
        float4 v = *(const float4*)(in + i);
        int r = __builtin_amdgcn_cvt_pk_fp8_f32(v.x, v.y, 0, false);
        r = __builtin_amdgcn_cvt_pk_fp8_f32(v.z, v.w, r, true);
        *(unsigned int*)(out + i) = (unsigned int)r;
    } else {
        for (int t = 0; t < 4 && i + t < n; ++t) out[i + t] = f2fp8(in[i + t]);
    }
}

// ---------- W[K,C] f32 -> Wt[C,K] bf16 ----------
__global__ void k_wT(const float* __restrict__ W, unsigned short* __restrict__ Wt, int K, int C) {
    int i = blockIdx.x * blockDim.x + threadIdx.x;
    if (i < K * C) {
        int k = i / C, c = i % C;
        Wt[c * K + k] = f2bf(W[i]);
    }
}

// ---------- binning pass 1: per-(block,bucket) counts (LDS atomics only) ----------
// cmat layout column-major: cmat[b * NBLKA + blk]
__global__ __launch_bounds__(256) void k_cnt(const int* __restrict__ row, int* __restrict__ cmat, int e) {
    __shared__ int hist[NB];
    int tid = threadIdx.x;
    int tile0 = blockIdx.x * TILEA;
    for (int b = tid; b < NB; b += 256) hist[b] = 0;
    __syncthreads();
#pragma unroll 8
    for (int t = 0; t < TILEA / 256; ++t) {
        int i = tile0 + t * 256 + tid;
        if (i < e) atomicAdd(&hist[row[i] >> 8], 1);
    }
    __syncthreads();
    for (int b = tid; b < NB; b += 256) cmat[b * NBLKA + blockIdx.x] = hist[b];
}

// ---------- binning pass 2: per-bucket exclusive scan of its block column + bucket total ----------
__global__ __launch_bounds__(512) void k_csum(int* __restrict__ cmat, int* __restrict__ btot) {
    __shared__ int lds[512];
    int b = blockIdx.x, tid = threadIdx.x;
    int v = (tid < NBLKA) ? cmat[b * NBLKA + tid] : 0;
    lds[tid] = v; __syncthreads();
    for (int off = 1; off < 512; off <<= 1) {
        int add = (tid >= off) ? lds[tid - off] : 0;
        __syncthreads();
        lds[tid] += add;
        __syncthreads();
    }
    if (tid < NBLKA) cmat[b * NBLKA + tid] = lds[tid] - v;  // within-bucket exclusive
    if (tid == 511) btot[b] = lds[511];                     // bucket total
}

// ---------- binning pass 3: exclusive scan of bucket totals -> bucket bases ----------
__global__ __launch_bounds__(512) void k_bscan(const int* __restrict__ btot, int* __restrict__ bbase) {
    __shared__ int lds[512];
    int tid = threadIdx.x;
    int v = (tid < NB) ? btot[tid] : 0;
    lds[tid] = v; __syncthreads();
    for (int off = 1; off < 512; off <<= 1) {
        int add = (tid >= off) ? lds[tid - off] : 0;
        __syncthreads();
        lds[tid] += add;
        __syncthreads();
    }
    if (tid < NB) bbase[tid] = lds[tid] - v;  // exclusive
    if (tid == NB - 1) bbase[NB] = lds[tid];  // total = EE
}

// ---------- binning pass 4: scatter to bucket-grouped tmp at scanned bases ----------
// record: high32 = val bits, low32 = col | (row&255)<<17   (col < 2^17)
__global__ __launch_bounds__(256) void k_scat2(const int* __restrict__ row, const int* __restrict__ col,
                                               const float* __restrict__ val, const int* __restrict__ cmat,
                                               const int* __restrict__ bbase,
                                               unsigned long long* __restrict__ tmp, int e) {
    __shared__ int hist[NB];
    __shared__ int base[NB];
    int tid = threadIdx.x;
    int tile0 = blockIdx.x * TILEA;
    for (int b = tid; b < NB; b += 256) {
        base[b] = bbase[b] + cmat[b * NBLKA + blockIdx.x];
        hist[b] = 0;
    }
    __syncthreads();
#pragma unroll 8
    for (int t = 0; t < TILEA / 256; ++t) {
        int i = tile0 + t * 256 + tid;
        if (i < e) {
            int r = row[i];
            int b = r >> 8;
            int rk = atomicAdd(&hist[b], 1);
            unsigned long long rec = ((unsigned long long)__builtin_bit_cast(unsigned int, val[i]) << 32)
                                   | (unsigned int)(col[i] | ((r & 255) << 17));
            tmp[base[b] + rk] = rec;
        }
    }
}

// ---------- binning pass 5: fused per-bucket row-hist + scan + rowp write + fine sort ----------
__global__ __launch_bounds__(256) void k_binB2(const int* __restrict__ bbase,
                                               const unsigned long long* __restrict__ tmp,
                                               unsigned long long* __restrict__ pairs,
                                               int* __restrict__ rowp, int n) {
    __shared__ int hist[256];
    __shared__ int cur[256];
    int tid = threadIdx.x;
    int b = blockIdx.x;
    int r0 = b << 8;
    int s = bbase[b], e = bbase[b + 1];
    hist[tid] = 0;
    __syncthreads();
    for (int i = s + tid; i < e; i += 256) {
        int r = ((unsigned int)tmp[i] >> 17) & 255;
        atomicAdd(&hist[r], 1);
    }
    __syncthreads();
    int v = hist[tid];
    for (int off = 1; off < 256; off <<= 1) {
        int add = (tid >= off) ? hist[tid - off] : 0;
        __syncthreads();
        hist[tid] += add;
        __syncthreads();
    }
    int pos0 = s + hist[tid] - v;  // row start (exclusive within bucket + bucket base)
    int rr = r0 + tid;
    if (rr < n) rowp[rr] = pos0;
    if (b == 0 && tid == 0) rowp[n] = bbase[NB];  // = EE
    cur[tid] = pos0;
    __syncthreads();
    for (int i = s + tid; i < e; i += 256) {
        unsigned long long rec = tmp[i];
        unsigned int w = (unsigned int)rec;
        int r = (w >> 17) & 255;
        int pos = atomicAdd(&cur[r], 1);
        pairs[pos] = (rec & 0xFFFFFFFF00000000ULL) | (unsigned long long)(w & 0x1FFFFu);
    }
}

// ---------- MFMA bf16 GEMM: C[M,256] = A[M,K] @ Bt[256,K]^T ----------
// BR: +bias+relu, bf16 output. F8: raw output quantized to fp8 (gather source for SpMM).
template <bool BR, bool F8>
__global__ __launch_bounds__(256) void k_gemm(const unsigned short* __restrict__ A,
                                              const unsigned short* __restrict__ Bt,
                                              const float* __restrict__ bias,
                                              unsigned short* __restrict__ C,
                                              unsigned char* __restrict__ C8,
                                              int M, int K) {
    int wave = threadIdx.x >> 6, lane = threadIdx.x & 63;
    int row0 = blockIdx.x * 64;
    int colBase = wave * 64;
    int hr = lane & 15, kg = lane >> 4;
    f32x4 acc[4][4];
#pragma unroll
    for (int r = 0; r < 4; ++r)
#pragma unroll
        for (int c = 0; c < 4; ++c) acc[r][c] = (f32x4){0.f, 0.f, 0.f, 0.f};

    for (int k0 = 0; k0 < K; k0 += 32) {
        int kk = k0 + kg * 8;
        bf16x8 af[4], bf_[4];
#pragma unroll
        for (int r = 0; r < 4; ++r) {
            int ar = row0 + r * 16 + hr;
            if (ar >= M) ar = M - 1;
            af[r] = *(const bf16x8*)(A + (size_t)ar * K + kk);
        }
#pragma unroll
        for (int c = 0; c < 4; ++c) {
            int bc = colBase + c * 16 + hr;
            bf_[c] = *(const bf16x8*)(Bt + (size_t)bc * K + kk);
        }
#pragma unroll
        for (int r = 0; r < 4; ++r)
#pragma unroll
            for (int c = 0; c < 4; ++c)
                acc[r][c] = __builtin_amdgcn_mfma_f32_16x16x32_bf16(af[r], bf_[c], acc[r][c], 0, 0, 0);
    }
    // C/D layout: col = lane&15, row = (lane>>4)*4 + reg
#pragma unroll
    for (int r = 0; r < 4; ++r)
#pragma unroll
        for (int c = 0; c < 4; ++c) {
            int col = colBase + c * 16 + hr;
            float bv = BR ? bias[col] : 0.f;
#pragma unroll
            for (int i = 0; i < 4; ++i) {
                int rr = row0 + r * 16 + kg * 4 + i;
                float v = acc[r][c][i];
                if (BR) v = fmaxf(v + bv, 0.f);
                if (rr < M) {
                    if (F8) C8[(size_t)rr * 256 + col] = f2fp8(v);
                    else    C[(size_t)rr * 256 + col] = f2bf(v);
                }
            }
        }
}

// ---------- SpMM D=256 over fp8 source: out[row] = relu(sum val*S[col] + bias), bf16 out ----------
__global__ __launch_bounds__(256) void k_spmm256(const int* __restrict__ rowp,
                                                 const unsigned long long* __restrict__ pairs,
                                                 const unsigned char* __restrict__ S,
                                                 const float* __restrict__ bias,
                                                 unsigned short* __restrict__ Hout, int n) {
    int lane = threadIdx.x & 63;
    int row = blockIdx.x * 4 + (threadIdx.x >> 6);
    if (row >= n) return;
    int s = rowp[row], e = rowp[row + 1];
    int f = lane * 4;   // 4 feats per lane, 64 lanes x 4B = full 256B fp8 row
    float a0 = 0.f, a1 = 0.f, a2 = 0.f, a3 = 0.f;
#pragma unroll 8
    for (int i = s; i < e; ++i) {
        unsigned long long p = pairs[i];
        unsigned int c = (unsigned int)p;
        float v = __builtin_bit_cast(float, (unsigned int)(p >> 32));
        int w = *(const int*)(S + (size_t)c * 256 + f);
        f32x2 dlo = __builtin_amdgcn_cvt_pk_f32_fp8(w, false);
        f32x2 dhi = __builtin_amdgcn_cvt_pk_f32_fp8(w, true);
        a0 += v * dlo.x; a1 += v * dlo.y; a2 += v * dhi.x; a3 += v * dhi.y;
    }
    float4 bv = *(const float4*)(bias + f);
    a0 = fmaxf(a0 + bv.x, 0.f);
    a1 = fmaxf(a1 + bv.y, 0.f);
    a2 = fmaxf(a2 + bv.z, 0.f);
    a3 = fmaxf(a3 + bv.w, 0.f);
    ushort4 o; o.x = f2bf(a0); o.y = f2bf(a1); o.z = f2bf(a2); o.w = f2bf(a3);
    *(ushort4*)(Hout + (size_t)row * 256 + f) = o;
}

// ---------- SpMM D=128 over fp8 x, no bias/relu: out = sum val*X[col], bf16 out ----------
__global__ __launch_bounds__(256) void k_spmm128(const int* __restrict__ rowp,
                                                 const unsigned long long* __restrict__ pairs,
                                                 const unsigned char* __restrict__ X,
                                                 unsigned short* __restrict__ Out, int n) {
    int lane = threadIdx.x & 63;
    int row = blockIdx.x * 4 + (threadIdx.x >> 6);
    if (row >= n) return;
    int s = rowp[row], e = rowp[row + 1];
    int f = lane * 2;   // 2 feats per lane, 64 lanes x 2B = full 128B fp8 row
    float a0 = 0.f, a1 = 0.f;
#pragma unroll 8
    for (int i = s; i < e; ++i) {
        unsigned long long p = pairs[i];
        unsigned int c = (unsigned int)p;
        float v = __builtin_bit_cast(float, (unsigned int)(p >> 32));
        int w = (int)*(const unsigned short*)(X + (size_t)c * 128 + f);
        f32x2 d = __builtin_amdgcn_cvt_pk_f32_fp8(w, false);
        a0 += v * d.x; a1 += v * d.y;
    }
    ushort2 o; o.x = f2bf(a0); o.y = f2bf(a1);
    *(ushort2*)(Out + (size_t)row * 128 + f) = o;
}

// ---------- FC + log_softmax: 16 lanes per node ----------
__global__ __launch_bounds__(256) void k_fc_lsm(const unsigned short* __restrict__ H,
                                                const float* __restrict__ Wf,
                                                const float* __restrict__ bf,
                                                float* __restrict__ out, int n) {
    int lane = threadIdx.x & 63;
    int wave = threadIdx.x >> 6;
    int sub = lane >> 4, j = lane & 15;
    int node = (blockIdx.x * 4 + wave) * 4 + sub;
    bool valid = node < n;
    int nd = valid ? node : (n - 1);
    float acc = 0.f;
    for (int f0 = 0; f0 < NH; f0 += 8) {
        union { uint4 u; unsigned short s[8]; } h;
        h.u = *(const uint4*)(H + (size_t)nd * NH + f0);
#pragma unroll
        for (int t = 0; t < 8; ++t) acc += b2f(h.s[t]) * Wf[(f0 + t) * NC + j];
    }
    acc += bf[j];
    float mx = acc;
    for (int m = 1; m < 16; m <<= 1) mx = fmaxf(mx, __shfl_xor(mx, m, 16));
    float sm = __expf(acc - mx);
    for (int m = 1; m < 16; m <<= 1) sm += __shfl_xor(sm, m, 16);
    float res = acc - mx - __logf(sm);
    if (valid) out[(size_t)node * NC + j] = res;
}

extern "C" void kernel_launch(void* const* d_in, const int* in_sizes, int n_in,
                              void* d_out, int out_size, void* d_ws, size_t ws_size,
                              hipStream_t stream) {
    const float* x      = (const float*)d_in[0];
    const float* adjval = (const float*)d_in[1];
    const float* w1 = (const float*)d_in[2];  const float* b1 = (const float*)d_in[3];
    const float* w2 = (const float*)d_in[4];  const float* b2 = (const float*)d_in[5];
    const float* w3 = (const float*)d_in[6];  const float* b3 = (const float*)d_in[7];
    const float* w4 = (const float*)d_in[8];  const float* b4 = (const float*)d_in[9];
    const float* fcw = (const float*)d_in[10]; const float* fcb = (const float*)d_in[11];
    const int* arow = (const int*)d_in[12];
    const int* acol = (const int*)d_in[13];
    float* out = (float*)d_out;

    char* ws = (char*)d_ws;
    size_t off = 0;
    auto alloc = [&](size_t bytes) { size_t o = off; off += (bytes + 255) & ~(size_t)255; return o; };

    unsigned char*  xb  = (unsigned char*)(ws + alloc((size_t)NN * NF));       // fp8 x
    unsigned short* Sb  = (unsigned short*)(ws + alloc((size_t)NN * NH * 2));  // layer-1 Ax bf16 / fp8 S
    unsigned short* H1  = (unsigned short*)(ws + alloc((size_t)NN * NH * 2));
    unsigned short* H2  = (unsigned short*)(ws + alloc((size_t)NN * NH * 2));
    unsigned short* Wt1 = (unsigned short*)(ws + alloc((size_t)NH * NF * 2));
    unsigned short* Wt2 = (unsigned short*)(ws + alloc((size_t)NH * NH * 2));
    unsigned short* Wt3 = (unsigned short*)(ws + alloc((size_t)NH * NH * 2));
    unsigned short* Wt4 = (unsigned short*)(ws + alloc((size_t)NH * NH * 2));
    int*   rowp   = (int*)(ws + alloc(((size_t)NN + 1) * 4));
    int*   cmat   = (int*)(ws + alloc((size_t)NB * NBLKA * 4));
    int*   btot   = (int*)(ws + alloc((size_t)NB * 4));
    int*   bbase  = (int*)(ws + alloc(((size_t)NB + 1) * 4));
    unsigned long long* pairs = (unsigned long long*)(ws + alloc((size_t)EE * 8));
    // tmp for binning reuses H2 (dead until layer 2; 51.2MB >= 25.6MB)
    unsigned long long* tmp = (unsigned long long*)H2;
    unsigned char* S8 = (unsigned char*)Sb;   // fp8 view of Sb for layers 2-4

    // --- input conversions ---
    k_cvt_fp8<<<(NN * NF / 4 + 255) / 256, 256, 0, stream>>>(x, xb, NN * NF);
    k_wT<<<(NF * NH + 255) / 256, 256, 0, stream>>>(w1, Wt1, NF, NH);
    k_wT<<<(NH * NH + 255) / 256, 256, 0, stream>>>(w2, Wt2, NH, NH);
    k_wT<<<(NH * NH + 255) / 256, 256, 0, stream>>>(w3, Wt3, NH, NH);
    k_wT<<<(NH * NH + 255) / 256, 256, 0, stream>>>(w4, Wt4, NH, NH);

    // --- CSR build: zero global atomics, rowp derived inside binning ---
    k_cnt<<<NBLKA, 256, 0, stream>>>(arow, cmat, EE);
    k_csum<<<NB, 512, 0, stream>>>(cmat, btot);
    k_bscan<<<1, 512, 0, stream>>>(btot, bbase);
    k_scat2<<<NBLKA, 256, 0, stream>>>(arow, acol, adjval, cmat, bbase, tmp, EE);
    k_binB2<<<NB, 256, 0, stream>>>(bbase, tmp, pairs, rowp, NN);

    int gGemm = (NN + 63) / 64;     // 1563
    int gSpmm = (NN + 3) / 4;       // 25000
    // --- layer 1 (reordered: (A@x)@W1, gathers fp8 x) ---
    k_spmm128<<<gSpmm, 256, 0, stream>>>(rowp, pairs, xb, Sb, NN);
    k_gemm<true, false><<<gGemm, 256, 0, stream>>>(Sb, Wt1, b1, H1, nullptr, NN, NF);
    // --- layer 2 (GEMM emits fp8 S, SpMM gathers fp8) ---
    k_gemm<false, true><<<gGemm, 256, 0, stream>>>(H1, Wt2, nullptr, nullptr, S8, NN, NH);
    k_spmm256<<<gSpmm, 256, 0, stream>>>(rowp, pairs, S8, b2, H2, NN);
    // --- layer 3 ---
    k_gemm<false, true><<<gGemm, 256, 0, stream>>>(H2, Wt3, nullptr, nullptr, S8, NN, NH);
    k_spmm256<<<gSpmm, 256, 0, stream>>>(rowp, pairs, S8, b3, H1, NN);
    // --- layer 4 ---
    k_gemm<false, true><<<gGemm, 256, 0, stream>>>(H1, Wt4, nullptr, nullptr, S8, NN, NH);
    k_spmm256<<<gSpmm, 256, 0, stream>>>(rowp, pairs, S8, b4, H2, NN);
    // --- FC + log_softmax ---
    k_fc_lsm<<<(NN + 15) / 16, 256, 0, stream>>>(H2, fcw, fcb, out, NN);
}

// Round 7
// 903.648 us; speedup vs baseline: 1.6914x; 1.1017x over previous
//
#include <hip/hip_runtime.h>
#include <hip/hip_bf16.h>

#define NN 100000
#define EE 3200000
#define NF 128
#define NH 256
#define NC 16
#define NB ((NN + 255) >> 8)          // 391 coarse buckets of 256 rows
#define TILEA 8192
#define NBLKA ((EE + TILEA - 1) / TILEA)  // 391 binning blocks

typedef __bf16 bf16x8 __attribute__((ext_vector_type(8)));
typedef float f32x4 __attribute__((ext_vector_type(4)));
typedef float f32x2 __attribute__((ext_vector_type(2)));

static __device__ __forceinline__ unsigned short f2bf(float f) {
    unsigned int u = __builtin_bit_cast(unsigned int, f);
    u += 0x7FFFu + ((u >> 16) & 1u);
    return (unsigned short)(u >> 16);
}
static __device__ __forceinline__ float b2f(unsigned short h) {
    unsigned int u = ((unsigned int)h) << 16;
    return __builtin_bit_cast(float, u);
}
static __device__ __forceinline__ unsigned char f2fp8(float v) {
    return (unsigned char)(__builtin_amdgcn_cvt_pk_fp8_f32(v, v, 0, false) & 0xFF);
}

#define GLOAD_LDS16(g, l) __builtin_amdgcn_global_load_lds( \
    (const __attribute__((address_space(1))) unsigned int*)(g), \
    (__attribute__((address_space(3))) unsigned int*)(l), 16, 0, 0)

// ---------- x f32 -> fp8 convert (vector x4) ----------
__global__ void k_cvt_fp8(const float* __restrict__ in, unsigned char* __restrict__ out, int n) {
    int i = (blockIdx.x * blockDim.x + threadIdx.x) * 4;
    if (i + 3 < n) {
        float4 v = *(const float4*)(in + i);
        int r = __builtin_amdgcn_cvt_pk_fp8_f32(v.x, v.y, 0, false);
        r = __builtin_amdgcn_cvt_pk_fp8_f32(v.z, v.w, r, true);
        *(unsigned int*)(out + i) = (unsigned int)r;
    } else {
        for (int t = 0; t < 4 && i + t < n; ++t) out[i + t] = f2fp8(in[i + t]);
    }
}

// ---------- all 4 weight transposes in one launch ----------
__global__ void k_wT4(const float* __restrict__ w1, const float* __restrict__ w2,
                      const float* __restrict__ w3, const float* __restrict__ w4,
                      unsigned short* __restrict__ Wt1, unsigned short* __restrict__ Wt2,
                      unsigned short* __restrict__ Wt3, unsigned short* __restrict__ Wt4) {
    int i = blockIdx.x * blockDim.x + threadIdx.x;
    if (i < NF * NH) {
        int k = i / NH, c = i % NH;
        Wt1[c * NF + k] = f2bf(w1[i]);
        return;
    }
    i -= NF * NH;
    int seg = i >> 16;          // / 65536 (NH*NH)
    int j = i & 65535;
    const float* W = (seg == 0) ? w2 : (seg == 1) ? w3 : w4;
    unsigned short* Wt = (seg == 0) ? Wt2 : (seg == 1) ? Wt3 : Wt4;
    int k = j >> 8, c = j & 255;
    Wt[c * NH + k] = f2bf(W[j]);
}

// ---------- binning pass 1: per-(block,bucket) counts (LDS atomics only) ----------
// cmat layout column-major: cmat[b * NBLKA + blk]
__global__ __launch_bounds__(256) void k_cnt(const int* __restrict__ row, int* __restrict__ cmat, int e) {
    __shared__ int hist[NB];
    int tid = threadIdx.x;
    int tile0 = blockIdx.x * TILEA;
    for (int b = tid; b < NB; b += 256) hist[b] = 0;
    __syncthreads();
#pragma unroll 8
    for (int t = 0; t < TILEA / 256; ++t) {
        int i = tile0 + t * 256 + tid;
        if (i < e) atomicAdd(&hist[row[i] >> 8], 1);
    }
    __syncthreads();
    for (int b = tid; b < NB; b += 256) cmat[b * NBLKA + blockIdx.x] = hist[b];
}

// ---------- binning pass 2: per-bucket exclusive scan of its block column + bucket total ----------
__global__ __launch_bounds__(512) void k_csum(int* __restrict__ cmat, int* __restrict__ btot) {
    __shared__ int lds[512];
    int b = blockIdx.x, tid = threadIdx.x;
    int v = (tid < NBLKA) ? cmat[b * NBLKA + tid] : 0;
    lds[tid] = v; __syncthreads();
    for (int off = 1; off < 512; off <<= 1) {
        int add = (tid >= off) ? lds[tid - off] : 0;
        __syncthreads();
        lds[tid] += add;
        __syncthreads();
    }
    if (tid < NBLKA) cmat[b * NBLKA + tid] = lds[tid] - v;  // within-bucket exclusive
    if (tid == 511) btot[b] = lds[511];                     // bucket total
}

// ---------- binning pass 3: exclusive scan of bucket totals -> bucket bases ----------
__global__ __launch_bounds__(512) void k_bscan(const int* __restrict__ btot, int* __restrict__ bbase) {
    __shared__ int lds[512];
    int tid = threadIdx.x;
    int v = (tid < NB) ? btot[tid] : 0;
    lds[tid] = v; __syncthreads();
    for (int off = 1; off < 512; off <<= 1) {
        int add = (tid >= off) ? lds[tid - off] : 0;
        __syncthreads();
        lds[tid] += add;
        __syncthreads();
    }
    if (tid < NB) bbase[tid] = lds[tid] - v;  // exclusive
    if (tid == NB - 1) bbase[NB] = lds[tid];  // total = EE
}

// ---------- binning pass 4: scatter to bucket-grouped tmp at scanned bases ----------
// record: high32 = val bits, low32 = col | (row&255)<<17   (col < 2^17)
__global__ __launch_bounds__(256) void k_scat2(const int* __restrict__ row, const int* __restrict__ col,
                                               const float* __restrict__ val, const int* __restrict__ cmat,
                                               const int* __restrict__ bbase,
                                               unsigned long long* __restrict__ tmp, int e) {
    __shared__ int hist[NB];
    __shared__ int base[NB];
    int tid = threadIdx.x;
    int tile0 = blockIdx.x * TILEA;
    for (int b = tid; b < NB; b += 256) {
        base[b] = bbase[b] + cmat[b * NBLKA + blockIdx.x];
        hist[b] = 0;
    }
    __syncthreads();
#pragma unroll 8
    for (int t = 0; t < TILEA / 256; ++t) {
        int i = tile0 + t * 256 + tid;
        if (i < e) {
            int r = row[i];
            int b = r >> 8;
            int rk = atomicAdd(&hist[b], 1);
            unsigned long long rec = ((unsigned long long)__builtin_bit_cast(unsigned int, val[i]) << 32)
                                   | (unsigned int)(col[i] | ((r & 255) << 17));
            tmp[base[b] + rk] = rec;
        }
    }
}

// ---------- binning pass 5: fused per-bucket row-hist + scan + rowp write + fine sort ----------
// pairs entry (4B): [val15 : 15][col : 17]; val15 = bf16(val) rounded to 15 bits.
// decode: v = bitcast(p & 0xFFFE0000), col = p & 0x1FFFF
__global__ __launch_bounds__(256) void k_binB2(const int* __restrict__ bbase,
                                               const unsigned long long* __restrict__ tmp,
                                               unsigned int* __restrict__ pairs,
                                               int* __restrict__ rowp, int n) {
    __shared__ int hist[256];
    __shared__ int cur[256];
    int tid = threadIdx.x;
    int b = blockIdx.x;
    int r0 = b << 8;
    int s = bbase[b], e = bbase[b + 1];
    hist[tid] = 0;
    __syncthreads();
    for (int i = s + tid; i < e; i += 256) {
        int r = ((unsigned int)tmp[i] >> 17) & 255;
        atomicAdd(&hist[r], 1);
    }
    __syncthreads();
    int v = hist[tid];
    for (int off = 1; off < 256; off <<= 1) {
        int add = (tid >= off) ? hist[tid - off] : 0;
        __syncthreads();
        hist[tid] += add;
        __syncthreads();
    }
    int pos0 = s + hist[tid] - v;  // row start (exclusive within bucket + bucket base)
    int rr = r0 + tid;
    if (rr < n) rowp[rr] = pos0;
    if (b == 0 && tid == 0) rowp[n] = bbase[NB];  // = EE
    cur[tid] = pos0;
    __syncthreads();
    for (int i = s + tid; i < e; i += 256) {
        unsigned long long rec = tmp[i];
        unsigned int w = (unsigned int)rec;
        int r = (w >> 17) & 255;
        unsigned int vb = (unsigned int)(rec >> 32);           // f32 bits
        unsigned int bf = (vb + 0x7FFFu + ((vb >> 16) & 1u)) >> 16;  // rounded bf16
        unsigned int v15 = (bf + 1u) >> 1;                     // round 16 -> 15 bits
        int pos = atomicAdd(&cur[r], 1);
        pairs[pos] = (v15 << 17) | (w & 0x1FFFFu);
    }
}

// ---------- MFMA bf16 GEMM, LDS-staged A (m97-style 2-phase): C[M,256] = A[M,K] @ Bt[256,K]^T ----------
// BR: +bias+relu, bf16 output. F8: raw output quantized to fp8 (gather source for SpMM).
template <bool BR, bool F8>
__global__ __launch_bounds__(256) void k_gemm(const unsigned short* __restrict__ A,
                                              const unsigned short* __restrict__ Bt,
                                              const float* __restrict__ bias,
                                              unsigned short* __restrict__ C,
                                              unsigned char* __restrict__ C8,
                                              int M, int K) {
    __shared__ unsigned short Atile[2][64 * 32];  // 2 x 4KB double buffer, [64 rows][32 k]
    int tid = threadIdx.x;
    int wave = tid >> 6, lane = tid & 63;
    int row0 = blockIdx.x * 64;
    int colBase = wave * 64;
    int hr = lane & 15, kg = lane >> 4;

    // staging: thread t covers LDS bytes [t*16, t*16+16) = row t>>2, elems (t&3)*8
    int srow = tid >> 2;
    int selem = (tid & 3) * 8;
    int arow = row0 + srow; if (arow >= M) arow = M - 1;
    const unsigned short* srcBase = A + (size_t)arow * K + selem;

    f32x4 acc[4][4];
#pragma unroll
    for (int r = 0; r < 4; ++r)
#pragma unroll
        for (int c = 0; c < 4; ++c) acc[r][c] = (f32x4){0.f, 0.f, 0.f, 0.f};

    // prologue: stage k0 = 0 into buf 0
    GLOAD_LDS16(srcBase, &Atile[0][0] + (size_t)tid * 8);
    __syncthreads();

    int cur = 0;
    for (int k0 = 0; k0 < K; k0 += 32) {
        if (k0 + 32 < K)
            GLOAD_LDS16(srcBase + k0 + 32, &Atile[cur ^ 1][0] + (size_t)tid * 8);
        bf16x8 af[4], bf_[4];
        int kk = k0 + kg * 8;
#pragma unroll
        for (int r = 0; r < 4; ++r)
            af[r] = *(const bf16x8*)(&Atile[cur][(r * 16 + hr) * 32 + kg * 8]);
#pragma unroll
        for (int c = 0; c < 4; ++c) {
            int bc = colBase + c * 16 + hr;
            bf_[c] = *(const bf16x8*)(Bt + (size_t)bc * K + kk);
        }
#pragma unroll
        for (int r = 0; r < 4; ++r)
#pragma unroll
            for (int c = 0; c < 4; ++c)
                acc[r][c] = __builtin_amdgcn_mfma_f32_16x16x32_bf16(af[r], bf_[c], acc[r][c], 0, 0, 0);
        __syncthreads();   // drains gload_lds (vmcnt 0) + barrier before buffer swap
        cur ^= 1;
    }
    // C/D layout: col = lane&15, row = (lane>>4)*4 + reg
#pragma unroll
    for (int r = 0; r < 4; ++r)
#pragma unroll
        for (int c = 0; c < 4; ++c) {
            int col = colBase + c * 16 + hr;
            float bv = BR ? bias[col] : 0.f;
#pragma unroll
            for (int i = 0; i < 4; ++i) {
                int rr = row0 + r * 16 + kg * 4 + i;
                float v = acc[r][c][i];
                if (BR) v = fmaxf(v + bv, 0.f);
                if (rr < M) {
                    if (F8) C8[(size_t)rr * 256 + col] = f2fp8(v);
                    else    C[(size_t)rr * 256 + col] = f2bf(v);
                }
            }
        }
}

// ---------- SpMM D=256 over fp8 source: out[row] = relu(sum val*S[col] + bias), bf16 out ----------
__global__ __launch_bounds__(256) void k_spmm256(const int* __restrict__ rowp,
                                                 const unsigned int* __restrict__ pairs,
                                                 const unsigned char* __restrict__ S,
                                                 const float* __restrict__ bias,
                                                 unsigned short* __restrict__ Hout, int n) {
    int lane = threadIdx.x & 63;
    int row = blockIdx.x * 4 + (threadIdx.x >> 6);
    if (row >= n) return;
    int s = rowp[row], e = rowp[row + 1];
    int f = lane * 4;   // 4 feats per lane, 64 lanes x 4B = full 256B fp8 row
    f32x2 a01 = {0.f, 0.f}, a23 = {0.f, 0.f};
#pragma unroll 8
    for (int i = s; i < e; ++i) {
        unsigned int p = pairs[i];
        unsigned int c = p & 0x1FFFFu;
        float v = __builtin_bit_cast(float, p & 0xFFFE0000u);
        int w = *(const int*)(S + (size_t)c * 256 + f);
        f32x2 dlo = __builtin_amdgcn_cvt_pk_f32_fp8(w, false);
        f32x2 dhi = __builtin_amdgcn_cvt_pk_f32_fp8(w, true);
        a01 += dlo * v; a23 += dhi * v;
    }
    float4 bv = *(const float4*)(bias + f);
    float a0 = fmaxf(a01.x + bv.x, 0.f);
    float a1 = fmaxf(a01.y + bv.y, 0.f);
    float a2 = fmaxf(a23.x + bv.z, 0.f);
    float a3 = fmaxf(a23.y + bv.w, 0.f);
    ushort4 o; o.x = f2bf(a0); o.y = f2bf(a1); o.z = f2bf(a2); o.w = f2bf(a3);
    *(ushort4*)(Hout + (size_t)row * 256 + f) = o;
}

// ---------- SpMM D=128 over fp8 x, no bias/relu: out = sum val*X[col], bf16 out ----------
__global__ __launch_bounds__(256) void k_spmm128(const int* __restrict__ rowp,
                                                 const unsigned int* __restrict__ pairs,
                                                 const unsigned char* __restrict__ X,
                                                 unsigned short* __restrict__ Out, int n) {
    int lane = threadIdx.x & 63;
    int row = blockIdx.x * 4 + (threadIdx.x >> 6);
    if (row >= n) return;
    int s = rowp[row], e = rowp[row + 1];
    int f = lane * 2;   // 2 feats per lane, 64 lanes x 2B = full 128B fp8 row
    f32x2 a01 = {0.f, 0.f};
#pragma unroll 8
    for (int i = s; i < e; ++i) {
        unsigned int p = pairs[i];
        unsigned int c = p & 0x1FFFFu;
        float v = __builtin_bit_cast(float, p & 0xFFFE0000u);
        int w = (int)*(const unsigned short*)(X + (size_t)c * 128 + f);
        f32x2 d = __builtin_amdgcn_cvt_pk_f32_fp8(w, false);
        a01 += d * v;
    }
    ushort2 o; o.x = f2bf(a01.x); o.y = f2bf(a01.y);
    *(ushort2*)(Out + (size_t)row * 128 + f) = o;
}

// ---------- FC + log_softmax: 16 lanes per node ----------
__global__ __launch_bounds__(256) void k_fc_lsm(const unsigned short* __restrict__ H,
                                                const float* __restrict__ Wf,
                                                const float* __restrict__ bf,
                                                float* __restrict__ out, int n) {
    int lane = threadIdx.x & 63;
    int wave = threadIdx.x >> 6;
    int sub = lane >> 4, j = lane & 15;
    int node = (blockIdx.x * 4 + wave) * 4 + sub;
    bool valid = node < n;
    int nd = valid ? node : (n - 1);
    float acc = 0.f;
    for (int f0 = 0; f0 < NH; f0 += 8) {
        union { uint4 u; unsigned short s[8]; } h;
        h.u = *(const uint4*)(H + (size_t)nd * NH + f0);
#pragma unroll
        for (int t = 0; t < 8; ++t) acc += b2f(h.s[t]) * Wf[(f0 + t) * NC + j];
    }
    acc += bf[j];
    float mx = acc;
    for (int m = 1; m < 16; m <<= 1) mx = fmaxf(mx, __shfl_xor(mx, m, 16));
    float sm = __expf(acc - mx);
    for (int m = 1; m < 16; m <<= 1) sm += __shfl_xor(sm, m, 16);
    float res = acc - mx - __logf(sm);
    if (valid) out[(size_t)node * NC + j] = res;
}

extern "C" void kernel_launch(void* const* d_in, const int* in_sizes, int n_in,
                              void* d_out, int out_size, void* d_ws, size_t ws_size,
                              hipStream_t stream) {
    const float* x      = (const float*)d_in[0];
    const float* adjval = (const float*)d_in[1];
    const float* w1 = (const float*)d_in[2];  const float* b1 = (const float*)d_in[3];
    const float* w2 = (const float*)d_in[4];  const float* b2 = (const float*)d_in[5];
    const float* w3 = (const float*)d_in[6];  const float* b3 = (const float*)d_in[7];
    const float* w4 = (const float*)d_in[8];  const float* b4 = (const float*)d_in[9];
    const float* fcw = (const float*)d_in[10]; const float* fcb = (const float*)d_in[11];
    const int* arow = (const int*)d_in[12];
    const int* acol = (const int*)d_in[13];
    float* out = (float*)d_out;

    char* ws = (char*)d_ws;
    size_t off = 0;
    auto alloc = [&](size_t bytes) { size_t o = off; off += (bytes + 255) & ~(size_t)255; return o; };

    unsigned char*  xb  = (unsigned char*)(ws + alloc((size_t)NN * NF));       // fp8 x
    unsigned short* Sb  = (unsigned short*)(ws + alloc((size_t)NN * NH * 2));  // layer-1 Ax bf16 / fp8 S
    unsigned short* H1  = (unsigned short*)(ws + alloc((size_t)NN * NH * 2));
    unsigned short* H2  = (unsigned short*)(ws + alloc((size_t)NN * NH * 2));
    unsigned short* Wt1 = (unsigned short*)(ws + alloc((size_t)NH * NF * 2));
    unsigned short* Wt2 = (unsigned short*)(ws + alloc((size_t)NH * NH * 2));
    unsigned short* Wt3 = (unsigned short*)(ws + alloc((size_t)NH * NH * 2));
    unsigned short* Wt4 = (unsigned short*)(ws + alloc((size_t)NH * NH * 2));
    int*   rowp   = (int*)(ws + alloc(((size_t)NN + 1) * 4));
    int*   cmat   = (int*)(ws + alloc((size_t)NB * NBLKA * 4));
    int*   btot   = (int*)(ws + alloc((size_t)NB * 4));
    int*   bbase  = (int*)(ws + alloc(((size_t)NB + 1) * 4));
    unsigned int* pairs = (unsigned int*)(ws + alloc((size_t)EE * 4));
    // tmp for binning reuses H2 (dead until layer 2; 51.2MB >= 25.6MB)
    unsigned long long* tmp = (unsigned long long*)H2;
    unsigned char* S8 = (unsigned char*)Sb;   // fp8 view of Sb for layers 2-4

    // --- input conversions ---
    k_cvt_fp8<<<(NN * NF / 4 + 255) / 256, 256, 0, stream>>>(x, xb, NN * NF);
    k_wT4<<<(NF * NH + 3 * NH * NH) / 256, 256, 0, stream>>>(w1, w2, w3, w4, Wt1, Wt2, Wt3, Wt4);

    // --- CSR build: zero global atomics, rowp derived inside binning ---
    k_cnt<<<NBLKA, 256, 0, stream>>>(arow, cmat, EE);
    k_csum<<<NB, 512, 0, stream>>>(cmat, btot);
    k_bscan<<<1, 512, 0, stream>>>(btot, bbase);
    k_scat2<<<NBLKA, 256, 0, stream>>>(arow, acol, adjval, cmat, bbase, tmp, EE);
    k_binB2<<<NB, 256, 0, stream>>>(bbase, tmp, pairs, rowp, NN);

    int gGemm = (NN + 63) / 64;     // 1563
    int gSpmm = (NN + 3) / 4;       // 25000
    // --- layer 1 (reordered: (A@x)@W1, gathers fp8 x) ---
    k_spmm128<<<gSpmm, 256, 0, stream>>>(rowp, pairs, xb, Sb, NN);
    k_gemm<true, false><<<gGemm, 256, 0, stream>>>(Sb, Wt1, b1, H1, nullptr, NN, NF);
    // --- layer 2 (GEMM emits fp8 S, SpMM gathers fp8) ---
    k_gemm<false, true><<<gGemm, 256, 0, stream>>>(H1, Wt2, nullptr, nullptr, S8, NN, NH);
    k_spmm256<<<gSpmm, 256, 0, stream>>>(rowp, pairs, S8, b2, H2, NN);
    // --- layer 3 ---
    k_gemm<false, true><<<gGemm, 256, 0, stream>>>(H2, Wt3, nullptr, nullptr, S8, NN, NH);
    k_spmm256<<<gSpmm, 256, 0, stream>>>(rowp, pairs, S8, b3, H1, NN);
    // --- layer 4 ---
    k_gemm<false, true><<<gGemm, 256, 0, stream>>>(H1, Wt4, nullptr, nullptr, S8, NN, NH);
    k_spmm256<<<gSpmm, 256, 0, stream>>>(rowp, pairs, S8, b4, H2, NN);
    // --- FC + log_softmax ---
    k_fc_lsm<<<(NN + 15) / 16, 256, 0, stream>>>(H2, fcw, fcb, out, NN);
}

// Round 8
// 880.076 us; speedup vs baseline: 1.7367x; 1.0268x over previous
//
#include <hip/hip_runtime.h>
#include <hip/hip_bf16.h>

#define NN 100000
#define EE 3200000
#define NF 128
#define NH 256
#define NC 16
#define NB ((NN + 255) >> 8)          // 391 coarse buckets of 256 rows
#define TILEA 8192
#define NBLKA ((EE + TILEA - 1) / TILEA)  // 391 binning blocks

typedef __bf16 bf16x8 __attribute__((ext_vector_type(8)));
typedef float f32x4 __attribute__((ext_vector_type(4)));
typedef float f32x2 __attribute__((ext_vector_type(2)));

static __device__ __forceinline__ unsigned short f2bf(float f) {
    unsigned int u = __builtin_bit_cast(unsigned int, f);
    u += 0x7FFFu + ((u >> 16) & 1u);
    return (unsigned short)(u >> 16);
}
static __device__ __forceinline__ float b2f(unsigned short h) {
    unsigned int u = ((unsigned int)h) << 16;
    return __builtin_bit_cast(float, u);
}
static __device__ __forceinline__ unsigned char f2fp8(float v) {
    return (unsigned char)(__builtin_amdgcn_cvt_pk_fp8_f32(v, v, 0, false) & 0xFF);
}

#define GLOAD_LDS16(g, l) __builtin_amdgcn_global_load_lds( \
    (const __attribute__((address_space(1))) unsigned int*)(g), \
    (__attribute__((address_space(3))) unsigned int*)(l), 16, 0, 0)

// ---------- x f32 -> fp8 convert (vector x4) ----------
__global__ void k_cvt_fp8(const float* __restrict__ in, unsigned char* __restrict__ out, int n) {
    int i = (blockIdx.x * blockDim.x + threadIdx.x) * 4;
    if (i + 3 < n) {
        float4 v = *(const float4*)(in + i);
        int r = __builtin_amdgcn_cvt_pk_fp8_f32(v.x, v.y, 0, false);
        r = __builtin_amdgcn_cvt_pk_fp8_f32(v.z, v.w, r, true);
        *(unsigned int*)(out + i) = (unsigned int)r;
    } else {
        for (int t = 0; t < 4 && i + t < n; ++t) out[i + t] = f2fp8(in[i + t]);
    }
}

// ---------- all 4 weight transposes in one launch ----------
__global__ void k_wT4(const float* __restrict__ w1, const float* __restrict__ w2,
                      const float* __restrict__ w3, const float* __restrict__ w4,
                      unsigned short* __restrict__ Wt1, unsigned short* __restrict__ Wt2,
                      unsigned short* __restrict__ Wt3, unsigned short* __restrict__ Wt4) {
    int i = blockIdx.x * blockDim.x + threadIdx.x;
    if (i < NF * NH) {
        int k = i / NH, c = i % NH;
        Wt1[c * NF + k] = f2bf(w1[i]);
        return;
    }
    i -= NF * NH;
    int seg = i >> 16;          // / 65536 (NH*NH)
    int j = i & 65535;
    const float* W = (seg == 0) ? w2 : (seg == 1) ? w3 : w4;
    unsigned short* Wt = (seg == 0) ? Wt2 : (seg == 1) ? Wt3 : Wt4;
    int k = j >> 8, c = j & 255;
    Wt[c * NH + k] = f2bf(W[j]);
}

// ---------- binning pass 1: per-(block,bucket) counts (LDS atomics only) ----------
// cmat layout column-major: cmat[b * NBLKA + blk]
__global__ __launch_bounds__(256) void k_cnt(const int* __restrict__ row, int* __restrict__ cmat, int e) {
    __shared__ int hist[NB];
    int tid = threadIdx.x;
    int tile0 = blockIdx.x * TILEA;
    for (int b = tid; b < NB; b += 256) hist[b] = 0;
    __syncthreads();
#pragma unroll 8
    for (int t = 0; t < TILEA / 256; ++t) {
        int i = tile0 + t * 256 + tid;
        if (i < e) atomicAdd(&hist[row[i] >> 8], 1);
    }
    __syncthreads();
    for (int b = tid; b < NB; b += 256) cmat[b * NBLKA + blockIdx.x] = hist[b];
}

// ---------- binning pass 2: per-bucket exclusive scan of its block column + bucket total ----------
__global__ __launch_bounds__(512) void k_csum(int* __restrict__ cmat, int* __restrict__ btot) {
    __shared__ int lds[512];
    int b = blockIdx.x, tid = threadIdx.x;
    int v = (tid < NBLKA) ? cmat[b * NBLKA + tid] : 0;
    lds[tid] = v; __syncthreads();
    for (int off = 1; off < 512; off <<= 1) {
        int add = (tid >= off) ? lds[tid - off] : 0;
        __syncthreads();
        lds[tid] += add;
        __syncthreads();
    }
    if (tid < NBLKA) cmat[b * NBLKA + tid] = lds[tid] - v;  // within-bucket exclusive
    if (tid == 511) btot[b] = lds[511];                     // bucket total
}

// ---------- binning pass 3: exclusive scan of bucket totals -> bucket bases ----------
__global__ __launch_bounds__(512) void k_bscan(const int* __restrict__ btot, int* __restrict__ bbase) {
    __shared__ int lds[512];
    int tid = threadIdx.x;
    int v = (tid < NB) ? btot[tid] : 0;
    lds[tid] = v; __syncthreads();
    for (int off = 1; off < 512; off <<= 1) {
        int add = (tid >= off) ? lds[tid - off] : 0;
        __syncthreads();
        lds[tid] += add;
        __syncthreads();
    }
    if (tid < NB) bbase[tid] = lds[tid] - v;  // exclusive
    if (tid == NB - 1) bbase[NB] = lds[tid];  // total = EE
}

// ---------- binning pass 4: scatter to bucket-grouped tmp at scanned bases ----------
// record: high32 = val bits, low32 = col | (row&255)<<17   (col < 2^17)
__global__ __launch_bounds__(256) void k_scat2(const int* __restrict__ row, const int* __restrict__ col,
                                               const float* __restrict__ val, const int* __restrict__ cmat,
                                               const int* __restrict__ bbase,
                                               unsigned long long* __restrict__ tmp, int e) {
    __shared__ int hist[NB];
    __shared__ int base[NB];
    int tid = threadIdx.x;
    int tile0 = blockIdx.x * TILEA;
    for (int b = tid; b < NB; b += 256) {
        base[b] = bbase[b] + cmat[b * NBLKA + blockIdx.x];
        hist[b] = 0;
    }
    __syncthreads();
#pragma unroll 8
    for (int t = 0; t < TILEA / 256; ++t) {
        int i = tile0 + t * 256 + tid;
        if (i < e) {
            int r = row[i];
            int b = r >> 8;
            int rk = atomicAdd(&hist[b], 1);
            unsigned long long rec = ((unsigned long long)__builtin_bit_cast(unsigned int, val[i]) << 32)
                                   | (unsigned int)(col[i] | ((r & 255) << 17));
            tmp[base[b] + rk] = rec;
        }
    }
}

// ---------- binning pass 5: fused per-bucket row-hist + scan + rowp write + fine sort ----------
// pairs entry (4B): [val15 : 15][col : 17]; val15 = bf16(val) rounded to 15 bits.
// decode: v = bitcast(p & 0xFFFE0000), col = p & 0x1FFFF
__global__ __launch_bounds__(256) void k_binB2(const int* __restrict__ bbase,
                                               const unsigned long long* __restrict__ tmp,
                                               unsigned int* __restrict__ pairs,
                                               int* __restrict__ rowp, int n) {
    __shared__ int hist[256];
    __shared__ int cur[256];
    int tid = threadIdx.x;
    int b = blockIdx.x;
    int r0 = b << 8;
    int s = bbase[b], e = bbase[b + 1];
    hist[tid] = 0;
    __syncthreads();
    for (int i = s + tid; i < e; i += 256) {
        int r = ((unsigned int)tmp[i] >> 17) & 255;
        atomicAdd(&hist[r], 1);
    }
    __syncthreads();
    int v = hist[tid];
    for (int off = 1; off < 256; off <<= 1) {
        int add = (tid >= off) ? hist[tid - off] : 0;
        __syncthreads();
        hist[tid] += add;
        __syncthreads();
    }
    int pos0 = s + hist[tid] - v;  // row start (exclusive within bucket + bucket base)
    int rr = r0 + tid;
    if (rr < n) rowp[rr] = pos0;
    if (b == 0 && tid == 0) rowp[n] = bbase[NB];  // = EE
    cur[tid] = pos0;
    __syncthreads();
    for (int i = s + tid; i < e; i += 256) {
        unsigned long long rec = tmp[i];
        unsigned int w = (unsigned int)rec;
        int r = (w >> 17) & 255;
        unsigned int vb = (unsigned int)(rec >> 32);           // f32 bits
        unsigned int bf = (vb + 0x7FFFu + ((vb >> 16) & 1u)) >> 16;  // rounded bf16
        unsigned int v15 = (bf + 1u) >> 1;                     // round 16 -> 15 bits
        int pos = atomicAdd(&cur[r], 1);
        pairs[pos] = (v15 << 17) | (w & 0x1FFFFu);
    }
}

// ---------- MFMA bf16 GEMM, LDS-staged A (m97-style 2-phase): C[M,256] = A[M,K] @ Bt[256,K]^T ----------
// BR: +bias+relu, bf16 output. F8: raw output quantized to fp8 (gather source for SpMM).
template <bool BR, bool F8>
__global__ __launch_bounds__(256) void k_gemm(const unsigned short* __restrict__ A,
                                              const unsigned short* __restrict__ Bt,
                                              const float* __restrict__ bias,
                                              unsigned short* __restrict__ C,
                                              unsigned char* __restrict__ C8,
                                              int M, int K) {
    __shared__ unsigned short Atile[2][64 * 32];  // 2 x 4KB double buffer, [64 rows][32 k]
    int tid = threadIdx.x;
    int wave = tid >> 6, lane = tid & 63;
    int row0 = blockIdx.x * 64;
    int colBase = wave * 64;
    int hr = lane & 15, kg = lane >> 4;

    // staging: thread t covers LDS bytes [t*16, t*16+16) = row t>>2, elems (t&3)*8
    int srow = tid >> 2;
    int selem = (tid & 3) * 8;
    int arow = row0 + srow; if (arow >= M) arow = M - 1;
    const unsigned short* srcBase = A + (size_t)arow * K + selem;

    f32x4 acc[4][4];
#pragma unroll
    for (int r = 0; r < 4; ++r)
#pragma unroll
        for (int c = 0; c < 4; ++c) acc[r][c] = (f32x4){0.f, 0.f, 0.f, 0.f};

    // prologue: stage k0 = 0 into buf 0
    GLOAD_LDS16(srcBase, &Atile[0][0] + (size_t)tid * 8);
    __syncthreads();

    int cur = 0;
    for (int k0 = 0; k0 < K; k0 += 32) {
        if (k0 + 32 < K)
            GLOAD_LDS16(srcBase + k0 + 32, &Atile[cur ^ 1][0] + (size_t)tid * 8);
        bf16x8 af[4], bf_[4];
        int kk = k0 + kg * 8;
#pragma unroll
        for (int r = 0; r < 4; ++r)
            af[r] = *(const bf16x8*)(&Atile[cur][(r * 16 + hr) * 32 + kg * 8]);
#pragma unroll
        for (int c = 0; c < 4; ++c) {
            int bc = colBase + c * 16 + hr;
            bf_[c] = *(const bf16x8*)(Bt + (size_t)bc * K + kk);
        }
#pragma unroll
        for (int r = 0; r < 4; ++r)
#pragma unroll
            for (int c = 0; c < 4; ++c)
                acc[r][c] = __builtin_amdgcn_mfma_f32_16x16x32_bf16(af[r], bf_[c], acc[r][c], 0, 0, 0);
        __syncthreads();   // drains gload_lds (vmcnt 0) + barrier before buffer swap
        cur ^= 1;
    }
    // C/D layout: col = lane&15, row = (lane>>4)*4 + reg
#pragma unroll
    for (int r = 0; r < 4; ++r)
#pragma unroll
        for (int c = 0; c < 4; ++c) {
            int col = colBase + c * 16 + hr;
            float bv = BR ? bias[col] : 0.f;
#pragma unroll
            for (int i = 0; i < 4; ++i) {
                int rr = row0 + r * 16 + kg * 4 + i;
                float v = acc[r][c][i];
                if (BR) v = fmaxf(v + bv, 0.f);
                if (rr < M) {
                    if (F8) C8[(size_t)rr * 256 + col] = f2fp8(v);
                    else    C[(size_t)rr * 256 + col] = f2bf(v);
                }
            }
        }
}

// ---------- SpMM D=256 over fp8 source: 2 edges per gather (half-wave x dwordx2 = 256B row) ----------
__global__ __launch_bounds__(256) void k_spmm256(const int* __restrict__ rowp,
                                                 const unsigned int* __restrict__ pairs,
                                                 const unsigned char* __restrict__ S,
                                                 const float* __restrict__ bias,
                                                 unsigned short* __restrict__ Hout, int n) {
    int lane = threadIdx.x & 63;
    int row = blockIdx.x * 4 + (threadIdx.x >> 6);
    if (row >= n) return;
    int s = rowp[row], e = rowp[row + 1];
    int half = lane >> 5;          // which edge of the pair
    int f = (lane & 31) * 8;       // 8 fp8 feats (8B) per lane
    f32x2 a01 = {0.f, 0.f}, a23 = {0.f, 0.f}, a45 = {0.f, 0.f}, a67 = {0.f, 0.f};
#pragma unroll 4
    for (int i = s; i < e; i += 2) {
        int idx = i + half;
        bool act = idx < e;
        unsigned int p = pairs[act ? idx : i];
        unsigned int c = p & 0x1FFFFu;
        float v = __builtin_bit_cast(float, p & 0xFFFE0000u);
        if (!act) v = 0.f;
        uint2 t = *(const uint2*)(S + (size_t)c * 256 + f);
        f32x2 d0 = __builtin_amdgcn_cvt_pk_f32_fp8((int)t.x, false);
        f32x2 d1 = __builtin_amdgcn_cvt_pk_f32_fp8((int)t.x, true);
        f32x2 d2 = __builtin_amdgcn_cvt_pk_f32_fp8((int)t.y, false);
        f32x2 d3 = __builtin_amdgcn_cvt_pk_f32_fp8((int)t.y, true);
        a01 += d0 * v; a23 += d1 * v; a45 += d2 * v; a67 += d3 * v;
    }
    float a0 = a01.x + __shfl_xor(a01.x, 32);
    float a1 = a01.y + __shfl_xor(a01.y, 32);
    float a2 = a23.x + __shfl_xor(a23.x, 32);
    float a3 = a23.y + __shfl_xor(a23.y, 32);
    float a4 = a45.x + __shfl_xor(a45.x, 32);
    float a5 = a45.y + __shfl_xor(a45.y, 32);
    float a6 = a67.x + __shfl_xor(a67.x, 32);
    float a7 = a67.y + __shfl_xor(a67.y, 32);
    if (half == 0) {
        float4 b0 = *(const float4*)(bias + f);
        float4 b1 = *(const float4*)(bias + f + 4);
        a0 = fmaxf(a0 + b0.x, 0.f); a1 = fmaxf(a1 + b0.y, 0.f);
        a2 = fmaxf(a2 + b0.z, 0.f); a3 = fmaxf(a3 + b0.w, 0.f);
        a4 = fmaxf(a4 + b1.x, 0.f); a5 = fmaxf(a5 + b1.y, 0.f);
        a6 = fmaxf(a6 + b1.z, 0.f); a7 = fmaxf(a7 + b1.w, 0.f);
        uint4 o;
        o.x = (unsigned int)f2bf(a0) | ((unsigned int)f2bf(a1) << 16);
        o.y = (unsigned int)f2bf(a2) | ((unsigned int)f2bf(a3) << 16);
        o.z = (unsigned int)f2bf(a4) | ((unsigned int)f2bf(a5) << 16);
        o.w = (unsigned int)f2bf(a6) | ((unsigned int)f2bf(a7) << 16);
        *(uint4*)(Hout + (size_t)row * 256 + f) = o;
    }
}

// ---------- SpMM D=128 over fp8 x: 2 edges per gather (half-wave x dword = 128B row) ----------
__global__ __launch_bounds__(256) void k_spmm128(const int* __restrict__ rowp,
                                                 const unsigned int* __restrict__ pairs,
                                                 const unsigned char* __restrict__ X,
                                                 unsigned short* __restrict__ Out, int n) {
    int lane = threadIdx.x & 63;
    int row = blockIdx.x * 4 + (threadIdx.x >> 6);
    if (row >= n) return;
    int s = rowp[row], e = rowp[row + 1];
    int half = lane >> 5;          // which edge of the pair
    int f = (lane & 31) * 4;       // 4 fp8 feats (4B) per lane
    f32x2 a01 = {0.f, 0.f}, a23 = {0.f, 0.f};
#pragma unroll 4
    for (int i = s; i < e; i += 2) {
        int idx = i + half;
        bool act = idx < e;
        unsigned int p = pairs[act ? idx : i];
        unsigned int c = p & 0x1FFFFu;
        float v = __builtin_bit_cast(float, p & 0xFFFE0000u);
        if (!act) v = 0.f;
        int w = *(const int*)(X + (size_t)c * 128 + f);
        f32x2 d0 = __builtin_amdgcn_cvt_pk_f32_fp8(w, false);
        f32x2 d1 = __builtin_amdgcn_cvt_pk_f32_fp8(w, true);
        a01 += d0 * v; a23 += d1 * v;
    }
    float a0 = a01.x + __shfl_xor(a01.x, 32);
    float a1 = a01.y + __shfl_xor(a01.y, 32);
    float a2 = a23.x + __shfl_xor(a23.x, 32);
    float a3 = a23.y + __shfl_xor(a23.y, 32);
    if (half == 0) {
        ushort4 o; o.x = f2bf(a0); o.y = f2bf(a1); o.z = f2bf(a2); o.w = f2bf(a3);
        *(ushort4*)(Out + (size_t)row * 128 + f) = o;
    }
}

// ---------- FC + log_softmax: 16 lanes per node ----------
__global__ __launch_bounds__(256) void k_fc_lsm(const unsigned short* __restrict__ H,
                                                const float* __restrict__ Wf,
                                                const float* __restrict__ bf,
                                                float* __restrict__ out, int n) {
    int lane = threadIdx.x & 63;
    int wave = threadIdx.x >> 6;
    int sub = lane >> 4, j = lane & 15;
    int node = (blockIdx.x * 4 + wave) * 4 + sub;
    bool valid = node < n;
    int nd = valid ? node : (n - 1);
    float acc = 0.f;
    for (int f0 = 0; f0 < NH; f0 += 8) {
        union { uint4 u; unsigned short s[8]; } h;
        h.u = *(const uint4*)(H + (size_t)nd * NH + f0);
#pragma unroll
        for (int t = 0; t < 8; ++t) acc += b2f(h.s[t]) * Wf[(f0 + t) * NC + j];
    }
    acc += bf[j];
    float mx = acc;
    for (int m = 1; m < 16; m <<= 1) mx = fmaxf(mx, __shfl_xor(mx, m, 16));
    float sm = __expf(acc - mx);
    for (int m = 1; m < 16; m <<= 1) sm += __shfl_xor(sm, m, 16);
    float res = acc - mx - __logf(sm);
    if (valid) out[(size_t)node * NC + j] = res;
}

extern "C" void kernel_launch(void* const* d_in, const int* in_sizes, int n_in,
                              void* d_out, int out_size, void* d_ws, size_t ws_size,
                              hipStream_t stream) {
    const float* x      = (const float*)d_in[0];
    const float* adjval = (const float*)d_in[1];
    const float* w1 = (const float*)d_in[2];  const float* b1 = (const float*)d_in[3];
    const float* w2 = (const float*)d_in[4];  const float* b2 = (const float*)d_in[5];
    const float* w3 = (const float*)d_in[6];  const float* b3 = (const float*)d_in[7];
    const float* w4 = (const float*)d_in[8];  const float* b4 = (const float*)d_in[9];
    const float* fcw = (const float*)d_in[10]; const float* fcb = (const float*)d_in[11];
    const int* arow = (const int*)d_in[12];
    const int* acol = (const int*)d_in[13];
    float* out = (float*)d_out;

    char* ws = (char*)d_ws;
    size_t off = 0;
    auto alloc = [&](size_t bytes) { size_t o = off; off += (bytes + 255) & ~(size_t)255; return o; };

    unsigned char*  xb  = (unsigned char*)(ws + alloc((size_t)NN * NF));       // fp8 x
    unsigned short* Sb  = (unsigned short*)(ws + alloc((size_t)NN * NH * 2));  // layer-1 Ax bf16 / fp8 S
    unsigned short* H1  = (unsigned short*)(ws + alloc((size_t)NN * NH * 2));
    unsigned short* H2  = (unsigned short*)(ws + alloc((size_t)NN * NH * 2));
    unsigned short* Wt1 = (unsigned short*)(ws + alloc((size_t)NH * NF * 2));
    unsigned short* Wt2 = (unsigned short*)(ws + alloc((size_t)NH * NH * 2));
    unsigned short* Wt3 = (unsigned short*)(ws + alloc((size_t)NH * NH * 2));
    unsigned short* Wt4 = (unsigned short*)(ws + alloc((size_t)NH * NH * 2));
    int*   rowp   = (int*)(ws + alloc(((size_t)NN + 1) * 4));
    int*   cmat   = (int*)(ws + alloc((size_t)NB * NBLKA * 4));
    int*   btot   = (int*)(ws + alloc((size_t)NB * 4));
    int*   bbase  = (int*)(ws + alloc(((size_t)NB + 1) * 4));
    unsigned int* pairs = (unsigned int*)(ws + alloc((size_t)EE * 4));
    // tmp for binning reuses H2 (dead until layer 2; 51.2MB >= 25.6MB)
    unsigned long long* tmp = (unsigned long long*)H2;
    unsigned char* S8 = (unsigned char*)Sb;   // fp8 view of Sb for layers 2-4

    // --- input conversions ---
    k_cvt_fp8<<<(NN * NF / 4 + 255) / 256, 256, 0, stream>>>(x, xb, NN * NF);
    k_wT4<<<(NF * NH + 3 * NH * NH) / 256, 256, 0, stream>>>(w1, w2, w3, w4, Wt1, Wt2, Wt3, Wt4);

    // --- CSR build: zero global atomics, rowp derived inside binning ---
    k_cnt<<<NBLKA, 256, 0, stream>>>(arow, cmat, EE);
    k_csum<<<NB, 512, 0, stream>>>(cmat, btot);
    k_bscan<<<1, 512, 0, stream>>>(btot, bbase);
    k_scat2<<<NBLKA, 256, 0, stream>>>(arow, acol, adjval, cmat, bbase, tmp, EE);
    k_binB2<<<NB, 256, 0, stream>>>(bbase, tmp, pairs, rowp, NN);

    int gGemm = (NN + 63) / 64;     // 1563
    int gSpmm = (NN + 3) / 4;       // 25000
    // --- layer 1 (reordered: (A@x)@W1, gathers fp8 x) ---
    k_spmm128<<<gSpmm, 256, 0, stream>>>(rowp, pairs, xb, Sb, NN);
    k_gemm<true, false><<<gGemm, 256, 0, stream>>>(Sb, Wt1, b1, H1, nullptr, NN, NF);
    // --- layer 2 (GEMM emits fp8 S, SpMM gathers fp8) ---
    k_gemm<false, true><<<gGemm, 256, 0, stream>>>(H1, Wt2, nullptr, nullptr, S8, NN, NH);
    k_spmm256<<<gSpmm, 256, 0, stream>>>(rowp, pairs, S8, b2, H2, NN);
    // --- layer 3 ---
    k_gemm<false, true><<<gGemm, 256, 0, stream>>>(H2, Wt3, nullptr, nullptr, S8, NN, NH);
    k_spmm256<<<gSpmm, 256, 0, stream>>>(rowp, pairs, S8, b3, H1, NN);
    // --- layer 4 ---
    k_gemm<false, true><<<gGemm, 256, 0, stream>>>(H1, Wt4, nullptr, nullptr, S8, NN, NH);
    k_spmm256<<<gSpmm, 256, 0, stream>>>(rowp, pairs, S8, b4, H2, NN);
    // --- FC + log_softmax ---
    k_fc_lsm<<<(NN + 15) / 16, 256, 0, stream>>>(H2, fcw, fcb, out, NN);
}

// Round 9
// 879.806 us; speedup vs baseline: 1.7373x; 1.0003x over previous
//
#include <hip/hip_runtime.h>
#include <hip/hip_bf16.h>

#define NN 100000
#define EE 3200000
#define NF 128
#define NH 256
#define NC 16
#define NB ((NN + 255) >> 8)          // 391 coarse buckets of 256 rows
#define TILEA 8192
#define NBLKA ((EE + TILEA - 1) / TILEA)  // 391 binning blocks

typedef __bf16 bf16x8 __attribute__((ext_vector_type(8)));
typedef float f32x4 __attribute__((ext_vector_type(4)));
typedef float f32x2 __attribute__((ext_vector_type(2)));

static __device__ __forceinline__ unsigned short f2bf(float f) {
    unsigned int u = __builtin_bit_cast(unsigned int, f);
    u += 0x7FFFu + ((u >> 16) & 1u);
    return (unsigned short)(u >> 16);
}
static __device__ __forceinline__ float b2f(unsigned short h) {
    unsigned int u = ((unsigned int)h) << 16;
    return __builtin_bit_cast(float, u);
}
static __device__ __forceinline__ unsigned char f2fp8(float v) {
    return (unsigned char)(__builtin_amdgcn_cvt_pk_fp8_f32(v, v, 0, false) & 0xFF);
}

#define GLOAD_LDS16(g, l) __builtin_amdgcn_global_load_lds( \
    (const __attribute__((address_space(1))) unsigned int*)(g), \
    (__attribute__((address_space(3))) unsigned int*)(l), 16, 0, 0)

// ---------- x f32 -> fp8 convert (vector x4) ----------
__global__ void k_cvt_fp8(const float* __restrict__ in, unsigned char* __restrict__ out, int n) {
    int i = (blockIdx.x * blockDim.x + threadIdx.x) * 4;
    if (i + 3 < n) {
        float4 v = *(const float4*)(in + i);
        int r = __builtin_amdgcn_cvt_pk_fp8_f32(v.x, v.y, 0, false);
        r = __builtin_amdgcn_cvt_pk_fp8_f32(v.z, v.w, r, true);
        *(unsigned int*)(out + i) = (unsigned int)r;
    } else {
        for (int t = 0; t < 4 && i + t < n; ++t) out[i + t] = f2fp8(in[i + t]);
    }
}

// ---------- all 4 weight transposes in one launch ----------
__global__ void k_wT4(const float* __restrict__ w1, const float* __restrict__ w2,
                      const float* __restrict__ w3, const float* __restrict__ w4,
                      unsigned short* __restrict__ Wt1, unsigned short* __restrict__ Wt2,
                      unsigned short* __restrict__ Wt3, unsigned short* __restrict__ Wt4) {
    int i = blockIdx.x * blockDim.x + threadIdx.x;
    if (i < NF * NH) {
        int k = i / NH, c = i % NH;
        Wt1[c * NF + k] = f2bf(w1[i]);
        return;
    }
    i -= NF * NH;
    int seg = i >> 16;          // / 65536 (NH*NH)
    int j = i & 65535;
    const float* W = (seg == 0) ? w2 : (seg == 1) ? w3 : w4;
    unsigned short* Wt = (seg == 0) ? Wt2 : (seg == 1) ? Wt3 : Wt4;
    int k = j >> 8, c = j & 255;
    Wt[c * NH + k] = f2bf(W[j]);
}

// ---------- binning pass 1: per-(block,bucket) counts (LDS atomics only) ----------
// cmat layout column-major: cmat[b * NBLKA + blk]
__global__ __launch_bounds__(256) void k_cnt(const int* __restrict__ row, int* __restrict__ cmat, int e) {
    __shared__ int hist[NB];
    int tid = threadIdx.x;
    int tile0 = blockIdx.x * TILEA;
    for (int b = tid; b < NB; b += 256) hist[b] = 0;
    __syncthreads();
#pragma unroll 8
    for (int t = 0; t < TILEA / 256; ++t) {
        int i = tile0 + t * 256 + tid;
        if (i < e) atomicAdd(&hist[row[i] >> 8], 1);
    }
    __syncthreads();
    for (int b = tid; b < NB; b += 256) cmat[b * NBLKA + blockIdx.x] = hist[b];
}

// ---------- binning pass 2: per-bucket exclusive scan of its block column + bucket total ----------
__global__ __launch_bounds__(512) void k_csum(int* __restrict__ cmat, int* __restrict__ btot) {
    __shared__ int lds[512];
    int b = blockIdx.x, tid = threadIdx.x;
    int v = (tid < NBLKA) ? cmat[b * NBLKA + tid] : 0;
    lds[tid] = v; __syncthreads();
    for (int off = 1; off < 512; off <<= 1) {
        int add = (tid >= off) ? lds[tid - off] : 0;
        __syncthreads();
        lds[tid] += add;
        __syncthreads();
    }
    if (tid < NBLKA) cmat[b * NBLKA + tid] = lds[tid] - v;  // within-bucket exclusive
    if (tid == 511) btot[b] = lds[511];                     // bucket total
}

// ---------- binning pass 3: exclusive scan of bucket totals -> bucket bases ----------
__global__ __launch_bounds__(512) void k_bscan(const int* __restrict__ btot, int* __restrict__ bbase) {
    __shared__ int lds[512];
    int tid = threadIdx.x;
    int v = (tid < NB) ? btot[tid] : 0;
    lds[tid] = v; __syncthreads();
    for (int off = 1; off < 512; off <<= 1) {
        int add = (tid >= off) ? lds[tid - off] : 0;
        __syncthreads();
        lds[tid] += add;
        __syncthreads();
    }
    if (tid < NB) bbase[tid] = lds[tid] - v;  // exclusive
    if (tid == NB - 1) bbase[NB] = lds[tid];  // total = EE
}

// ---------- binning pass 4: scatter to bucket-grouped tmp at scanned bases ----------
// record: high32 = val bits, low32 = col | (row&255)<<17   (col < 2^17)
__global__ __launch_bounds__(256) void k_scat2(const int* __restrict__ row, const int* __restrict__ col,
                                               const float* __restrict__ val, const int* __restrict__ cmat,
                                               const int* __restrict__ bbase,
                                               unsigned long long* __restrict__ tmp, int e) {
    __shared__ int hist[NB];
    __shared__ int base[NB];
    int tid = threadIdx.x;
    int tile0 = blockIdx.x * TILEA;
    for (int b = tid; b < NB; b += 256) {
        base[b] = bbase[b] + cmat[b * NBLKA + blockIdx.x];
        hist[b] = 0;
    }
    __syncthreads();
#pragma unroll 8
    for (int t = 0; t < TILEA / 256; ++t) {
        int i = tile0 + t * 256 + tid;
        if (i < e) {
            int r = row[i];
            int b = r >> 8;
            int rk = atomicAdd(&hist[b], 1);
            unsigned long long rec = ((unsigned long long)__builtin_bit_cast(unsigned int, val[i]) << 32)
                                   | (unsigned int)(col[i] | ((r & 255) << 17));
            tmp[base[b] + rk] = rec;
        }
    }
}

// ---------- binning pass 5: fused per-bucket (row, col-window) counting sort + rowp ----------
// sort key = (row&255)<<5 | col>>12  (32 column windows of 4096 cols = 1MB of fp8 S each).
// Within-row column-window order gives concurrently-running SpMM waves an emergent
// synchronized sweep over S -> gather working set shrinks to a few windows -> L2-resident.
// pairs entry (4B): [val15 : 15][col : 17]; decode v = bitcast(p & 0xFFFE0000), col = p & 0x1FFFF
__global__ __launch_bounds__(256) void k_binB2(const int* __restrict__ bbase,
                                               const unsigned long long* __restrict__ tmp,
                                               unsigned int* __restrict__ pairs,
                                               int* __restrict__ rowp, int n) {
    __shared__ int hist[8192];   // (row&255)<<5 | win
    __shared__ int part[256];
    int tid = threadIdx.x;
    int b = blockIdx.x;
    int r0 = b << 8;
    int s = bbase[b], e = bbase[b + 1];
    int base = tid * 32;
#pragma unroll
    for (int j = 0; j < 32; ++j) hist[base + j] = 0;
    __syncthreads();
    // pass 1: count keys
    for (int i = s + tid; i < e; i += 256) {
        unsigned int w = (unsigned int)tmp[i];
        int key = (((w >> 17) & 255) << 5) | ((w & 0x1FFFFu) >> 12);
        atomicAdd(&hist[key], 1);
    }
    __syncthreads();
    // hierarchical exclusive scan of hist[8192]: per-thread serial over 32, block scan of partials
    int tot = 0;
#pragma unroll
    for (int j = 0; j < 32; ++j) { int x = hist[base + j]; hist[base + j] = tot; tot += x; }
    part[tid] = tot;
    __syncthreads();
    int v = tot;
    for (int off = 1; off < 256; off <<= 1) {
        int add = (tid >= off) ? part[tid - off] : 0;
        __syncthreads();
        part[tid] += add;
        __syncthreads();
    }
    int offex = part[tid] - v;   // exclusive block offset
#pragma unroll
    for (int j = 0; j < 32; ++j) hist[base + j] += offex;
    __syncthreads();
    // rowp from row starts (key r<<5) BEFORE scatter mutates hist
    int rr = r0 + tid;
    if (rr < n) rowp[rr] = s + hist[tid << 5];
    if (b == 0 && tid == 0) rowp[n] = bbase[NB];  // = EE
    __syncthreads();
    // pass 2: scatter in (row, col-window) order
    for (int i = s + tid; i < e; i += 256) {
        unsigned long long rec = tmp[i];
        unsigned int w = (unsigned int)rec;
        int key = (((w >> 17) & 255) << 5) | ((w & 0x1FFFFu) >> 12);
        unsigned int vb = (unsigned int)(rec >> 32);           // f32 bits
        unsigned int bf = (vb + 0x7FFFu + ((vb >> 16) & 1u)) >> 16;  // rounded bf16
        unsigned int v15 = (bf + 1u) >> 1;                     // round 16 -> 15 bits
        int pos = s + atomicAdd(&hist[key], 1);
        pairs[pos] = (v15 << 17) | (w & 0x1FFFFu);
    }
}

// ---------- MFMA bf16 GEMM, LDS-staged A (m97-style 2-phase): C[M,256] = A[M,K] @ Bt[256,K]^T ----------
// BR: +bias+relu, bf16 output. F8: raw output quantized to fp8 (gather source for SpMM).
template <bool BR, bool F8>
__global__ __launch_bounds__(256) void k_gemm(const unsigned short* __restrict__ A,
                                              const unsigned short* __restrict__ Bt,
                                              const float* __restrict__ bias,
                                              unsigned short* __restrict__ C,
                                              unsigned char* __restrict__ C8,
                                              int M, int K) {
    __shared__ unsigned short Atile[2][64 * 32];  // 2 x 4KB double buffer, [64 rows][32 k]
    int tid = threadIdx.x;
    int wave = tid >> 6, lane = tid & 63;
    int row0 = blockIdx.x * 64;
    int colBase = wave * 64;
    int hr = lane & 15, kg = lane >> 4;

    // staging: thread t covers LDS bytes [t*16, t*16+16) = row t>>2, elems (t&3)*8
    int srow = tid >> 2;
    int selem = (tid & 3) * 8;
    int arow = row0 + srow; if (arow >= M) arow = M - 1;
    const unsigned short* srcBase = A + (size_t)arow * K + selem;

    f32x4 acc[4][4];
#pragma unroll
    for (int r = 0; r < 4; ++r)
#pragma unroll
        for (int c = 0; c < 4; ++c) acc[r][c] = (f32x4){0.f, 0.f, 0.f, 0.f};

    // prologue: stage k0 = 0 into buf 0
    GLOAD_LDS16(srcBase, &Atile[0][0] + (size_t)tid * 8);
    __syncthreads();

    int cur = 0;
    for (int k0 = 0; k0 < K; k0 += 32) {
        if (k0 + 32 < K)
            GLOAD_LDS16(srcBase + k0 + 32, &Atile[cur ^ 1][0] + (size_t)tid * 8);
        bf16x8 af[4], bf_[4];
        int kk = k0 + kg * 8;
#pragma unroll
        for (int r = 0; r < 4; ++r)
            af[r] = *(const bf16x8*)(&Atile[cur][(r * 16 + hr) * 32 + kg * 8]);
#pragma unroll
        for (int c = 0; c < 4; ++c) {
            int bc = colBase + c * 16 + hr;
            bf_[c] = *(const bf16x8*)(Bt + (size_t)bc * K + kk);
        }
#pragma unroll
        for (int r = 0; r < 4; ++r)
#pragma unroll
            for (int c = 0; c < 4; ++c)
                acc[r][c] = __builtin_amdgcn_mfma_f32_16x16x32_bf16(af[r], bf_[c], acc[r][c], 0, 0, 0);
        __syncthreads();   // drains gload_lds (vmcnt 0) + barrier before buffer swap
        cur ^= 1;
    }
    // C/D layout: col = lane&15, row = (lane>>4)*4 + reg
#pragma unroll
    for (int r = 0; r < 4; ++r)
#pragma unroll
        for (int c = 0; c < 4; ++c) {
            int col = colBase + c * 16 + hr;
            float bv = BR ? bias[col] : 0.f;
#pragma unroll
            for (int i = 0; i < 4; ++i) {
                int rr = row0 + r * 16 + kg * 4 + i;
                float v = acc[r][c][i];
                if (BR) v = fmaxf(v + bv, 0.f);
                if (rr < M) {
                    if (F8) C8[(size_t)rr * 256 + col] = f2fp8(v);
                    else    C[(size_t)rr * 256 + col] = f2bf(v);
                }
            }
        }
}

// ---------- SpMM D=256 over fp8 source: 2 edges per gather (half-wave x dwordx2 = 256B row) ----------
__global__ __launch_bounds__(256) void k_spmm256(const int* __restrict__ rowp,
                                                 const unsigned int* __restrict__ pairs,
                                                 const unsigned char* __restrict__ S,
                                                 const float* __restrict__ bias,
                                                 unsigned short* __restrict__ Hout, int n) {
    int lane = threadIdx.x & 63;
    int row = blockIdx.x * 4 + (threadIdx.x >> 6);
    if (row >= n) return;
    int s = rowp[row], e = rowp[row + 1];
    int half = lane >> 5;          // which edge of the pair
    int f = (lane & 31) * 8;       // 8 fp8 feats (8B) per lane
    f32x2 a01 = {0.f, 0.f}, a23 = {0.f, 0.f}, a45 = {0.f, 0.f}, a67 = {0.f, 0.f};
#pragma unroll 4
    for (int i = s; i < e; i += 2) {
        int idx = i + half;
        bool act = idx < e;
        unsigned int p = pairs[act ? idx : i];
        unsigned int c = p & 0x1FFFFu;
        float v = __builtin_bit_cast(float, p & 0xFFFE0000u);
        if (!act) v = 0.f;
        uint2 t = *(const uint2*)(S + (size_t)c * 256 + f);
        f32x2 d0 = __builtin_amdgcn_cvt_pk_f32_fp8((int)t.x, false);
        f32x2 d1 = __builtin_amdgcn_cvt_pk_f32_fp8((int)t.x, true);
        f32x2 d2 = __builtin_amdgcn_cvt_pk_f32_fp8((int)t.y, false);
        f32x2 d3 = __builtin_amdgcn_cvt_pk_f32_fp8((int)t.y, true);
        a01 += d0 * v; a23 += d1 * v; a45 += d2 * v; a67 += d3 * v;
    }
    float a0 = a01.x + __shfl_xor(a01.x, 32);
    float a1 = a01.y + __shfl_xor(a01.y, 32);
    float a2 = a23.x + __shfl_xor(a23.x, 32);
    float a3 = a23.y + __shfl_xor(a23.y, 32);
    float a4 = a45.x + __shfl_xor(a45.x, 32);
    float a5 = a45.y + __shfl_xor(a45.y, 32);
    float a6 = a67.x + __shfl_xor(a67.x, 32);
    float a7 = a67.y + __shfl_xor(a67.y, 32);
    if (half == 0) {
        float4 b0 = *(const float4*)(bias + f);
        float4 b1 = *(const float4*)(bias + f + 4);
        a0 = fmaxf(a0 + b0.x, 0.f); a1 = fmaxf(a1 + b0.y, 0.f);
        a2 = fmaxf(a2 + b0.z, 0.f); a3 = fmaxf(a3 + b0.w, 0.f);
        a4 = fmaxf(a4 + b1.x, 0.f); a5 = fmaxf(a5 + b1.y, 0.f);
        a6 = fmaxf(a6 + b1.z, 0.f); a7 = fmaxf(a7 + b1.w, 0.f);
        uint4 o;
        o.x = (unsigned int)f2bf(a0) | ((unsigned int)f2bf(a1) << 16);
        o.y = (unsigned int)f2bf(a2) | ((unsigned int)f2bf(a3) << 16);
        o.z = (unsigned int)f2bf(a4) | ((unsigned int)f2bf(a5) << 16);
        o.w = (unsigned int)f2bf(a6) | ((unsigned int)f2bf(a7) << 16);
        *(uint4*)(Hout + (size_t)row * 256 + f) = o;
    }
}

// ---------- SpMM D=128 over fp8 x: 2 edges per gather (half-wave x dword = 128B row) ----------
__global__ __launch_bounds__(256) void k_spmm128(const int* __restrict__ rowp,
                                                 const unsigned int* __restrict__ pairs,
                                                 const unsigned char* __restrict__ X,
                                                 unsigned short* __restrict__ Out, int n) {
    int lane = threadIdx.x & 63;
    int row = blockIdx.x * 4 + (threadIdx.x >> 6);
    if (row >= n) return;
    int s = rowp[row], e = rowp[row + 1];
    int half = lane >> 5;          // which edge of the pair
    int f = (lane & 31) * 4;       // 4 fp8 feats (4B) per lane
    f32x2 a01 = {0.f, 0.f}, a23 = {0.f, 0.f};
#pragma unroll 4
    for (int i = s; i < e; i += 2) {
        int idx = i + half;
        bool act = idx < e;
        unsigned int p = pairs[act ? idx : i];
        unsigned int c = p & 0x1FFFFu;
        float v = __builtin_bit_cast(float, p & 0xFFFE0000u);
        if (!act) v = 0.f;
        int w = *(const int*)(X + (size_t)c * 128 + f);
        f32x2 d0 = __builtin_amdgcn_cvt_pk_f32_fp8(w, false);
        f32x2 d1 = __builtin_amdgcn_cvt_pk_f32_fp8(w, true);
        a01 += d0 * v; a23 += d1 * v;
    }
    float a0 = a01.x + __shfl_xor(a01.x, 32);
    float a1 = a01.y + __shfl_xor(a01.y, 32);
    float a2 = a23.x + __shfl_xor(a23.x, 32);
    float a3 = a23.y + __shfl_xor(a23.y, 32);
    if (half == 0) {
        ushort4 o; o.x = f2bf(a0); o.y = f2bf(a1); o.z = f2bf(a2); o.w = f2bf(a3);
        *(ushort4*)(Out + (size_t)row * 128 + f) = o;
    }
}

// ---------- FC + log_softmax: 16 lanes per node ----------
__global__ __launch_bounds__(256) void k_fc_lsm(const unsigned short* __restrict__ H,
                                                const float* __restrict__ Wf,
                                                const float* __restrict__ bf,
                                                float* __restrict__ out, int n) {
    int lane = threadIdx.x & 63;
    int wave = threadIdx.x >> 6;
    int sub = lane >> 4, j = lane & 15;
    int node = (blockIdx.x * 4 + wave) * 4 + sub;
    bool valid = node < n;
    int nd = valid ? node : (n - 1);
    float acc = 0.f;
    for (int f0 = 0; f0 < NH; f0 += 8) {
        union { uint4 u; unsigned short s[8]; } h;
        h.u = *(const uint4*)(H + (size_t)nd * NH + f0);
#pragma unroll
        for (int t = 0; t < 8; ++t) acc += b2f(h.s[t]) * Wf[(f0 + t) * NC + j];
    }
    acc += bf[j];
    float mx = acc;
    for (int m = 1; m < 16; m <<= 1) mx = fmaxf(mx, __shfl_xor(mx, m, 16));
    float sm = __expf(acc - mx);
    for (int m = 1; m < 16; m <<= 1) sm += __shfl_xor(sm, m, 16);
    float res = acc - mx - __logf(sm);
    if (valid) out[(size_t)node * NC + j] = res;
}

extern "C" void kernel_launch(void* const* d_in, const int* in_sizes, int n_in,
                              void* d_out, int out_size, void* d_ws, size_t ws_size,
                              hipStream_t stream) {
    const float* x      = (const float*)d_in[0];
    const float* adjval = (const float*)d_in[1];
    const float* w1 = (const float*)d_in[2];  const float* b1 = (const float*)d_in[3];
    const float* w2 = (const float*)d_in[4];  const float* b2 = (const float*)d_in[5];
    const float* w3 = (const float*)d_in[6];  const float* b3 = (const float*)d_in[7];
    const float* w4 = (const float*)d_in[8];  const float* b4 = (const float*)d_in[9];
    const float* fcw = (const float*)d_in[10]; const float* fcb = (const float*)d_in[11];
    const int* arow = (const int*)d_in[12];
    const int* acol = (const int*)d_in[13];
    float* out = (float*)d_out;

    char* ws = (char*)d_ws;
    size_t off = 0;
    auto alloc = [&](size_t bytes) { size_t o = off; off += (bytes + 255) & ~(size_t)255; return o; };

    unsigned char*  xb  = (unsigned char*)(ws + alloc((size_t)NN * NF));       // fp8 x
    unsigned short* Sb  = (unsigned short*)(ws + alloc((size_t)NN * NH * 2));  // layer-1 Ax bf16 / fp8 S
    unsigned short* H1  = (unsigned short*)(ws + alloc((size_t)NN * NH * 2));
    unsigned short* H2  = (unsigned short*)(ws + alloc((size_t)NN * NH * 2));
    unsigned short* Wt1 = (unsigned short*)(ws + alloc((size_t)NH * NF * 2));
    unsigned short* Wt2 = (unsigned short*)(ws + alloc((size_t)NH * NH * 2));
    unsigned short* Wt3 = (unsigned short*)(ws + alloc((size_t)NH * NH * 2));
    unsigned short* Wt4 = (unsigned short*)(ws + alloc((size_t)NH * NH * 2));
    int*   rowp   = (int*)(ws + alloc(((size_t)NN + 1) * 4));
    int*   cmat   = (int*)(ws + alloc((size_t)NB * NBLKA * 4));
    int*   btot   = (int*)(ws + alloc((size_t)NB * 4));
    int*   bbase  = (int*)(ws + alloc(((size_t)NB + 1) * 4));
    unsigned int* pairs = (unsigned int*)(ws + alloc((size_t)EE * 4));
    // tmp for binning reuses H2 (dead until layer 2; 51.2MB >= 25.6MB)
    unsigned long long* tmp = (unsigned long long*)H2;
    unsigned char* S8 = (unsigned char*)Sb;   // fp8 view of Sb for layers 2-4

    // --- input conversions ---
    k_cvt_fp8<<<(NN * NF / 4 + 255) / 256, 256, 0, stream>>>(x, xb, NN * NF);
    k_wT4<<<(NF * NH + 3 * NH * NH) / 256, 256, 0, stream>>>(w1, w2, w3, w4, Wt1, Wt2, Wt3, Wt4);

    // --- CSR build: zero global atomics, rowp derived inside binning, col-window sorted ---
    k_cnt<<<NBLKA, 256, 0, stream>>>(arow, cmat, EE);
    k_csum<<<NB, 512, 0, stream>>>(cmat, btot);
    k_bscan<<<1, 512, 0, stream>>>(btot, bbase);
    k_scat2<<<NBLKA, 256, 0, stream>>>(arow, acol, adjval, cmat, bbase, tmp, EE);
    k_binB2<<<NB, 256, 0, stream>>>(bbase, tmp, pairs, rowp, NN);

    int gGemm = (NN + 63) / 64;     // 1563
    int gSpmm = (NN + 3) / 4;       // 25000
    // --- layer 1 (reordered: (A@x)@W1, gathers fp8 x) ---
    k_spmm128<<<gSpmm, 256, 0, stream>>>(rowp, pairs, xb, Sb, NN);
    k_gemm<true, false><<<gGemm, 256, 0, stream>>>(Sb, Wt1, b1, H1, nullptr, NN, NF);
    // --- layer 2 (GEMM emits fp8 S, SpMM gathers fp8) ---
    k_gemm<false, true><<<gGemm, 256, 0, stream>>>(H1, Wt2, nullptr, nullptr, S8, NN, NH);
    k_spmm256<<<gSpmm, 256, 0, stream>>>(rowp, pairs, S8, b2, H2, NN);
    // --- layer 3 ---
    k_gemm<false, true><<<gGemm, 256, 0, stream>>>(H2, Wt3, nullptr, nullptr, S8, NN, NH);
    k_spmm256<<<gSpmm, 256, 0, stream>>>(rowp, pairs, S8, b3, H1, NN);
    // --- layer 4 ---
    k_gemm<false, true><<<gGemm, 256, 0, stream>>>(H1, Wt4, nullptr, nullptr, S8, NN, NH);
    k_spmm256<<<gSpmm, 256, 0, stream>>>(rowp, pairs, S8, b4, H2, NN);
    // --- FC + log_softmax ---
    k_fc_lsm<<<(NN + 15) / 16, 256, 0, stream>>>(H2, fcw, fcb, out, NN);
}